// Round 1
// 1875.879 us; speedup vs baseline: 1.0656x; 1.0656x over previous
//
#include <hip/hip_runtime.h>

// ============================================================================
// 2-layer tanh RNN (B=128,S=512,IN=128,H=512) + linear head (C=1000) + logsoftmax
//
// Round-11: R10 structure, but recurrence moved from 1 wave/SIMD to 2 waves/SIMD.
//   R10 step = 3990 cyc with ~2000 cyc stall: single-wave-per-SIMD cannot cover
//   ds_read latency after the barrier, 8-deep dependent MFMA accumulation
//   chains, or trans-pipe (exp2/rcp) latency in the epilogue.
//   Fix: 8 WGs x 512 thr (8 waves, 2/SIMD). Each wave owns 4 j-tiles (not 8):
//   wa[4][8] = 128 AGPRs + ~100 VGPR working set fits the 256-reg budget of
//   2 waves/SIMD, so the co-resident wave's issue covers all latency classes.
//   Per-SIMD work per step unchanged (64 MFMAs, same VALU/trans totals).
//   Everything else identical to R10: full W_hh i8 in AGPRs, h i8 LDS dbuf
//   with 16B-granule swizzle g' = g ^ lm, lgkm-only barrier, xv prefetched one
//   full step ahead, MFMA(j);EPI(j-1) interleave, t-loop unrolled x2 so the
//   LDS buffer parity is a compile-time immediate, R9 numerics (xp pre-scaled
//   by 2*log2(e), sc2 absorbs dequant, bf16->f32 via v_perm).
//
// ws layout: bufA = ws (64 MB): xp0/hs0 in place; later Wq1 head + hlast @
//            +1MB. bufB = ws+64MB: Wq0/sc0 head (dead after rec0), later xp1.
// ============================================================================

using short8  = __attribute__((ext_vector_type(8))) short;
using floatx4 = __attribute__((ext_vector_type(4))) float;
using i32x4   = __attribute__((ext_vector_type(4))) int;
using f32x4   = __attribute__((ext_vector_type(4))) float;

#define DEV static __device__ __forceinline__
#define PINA(x) asm volatile("" : "+a"(x))
#define PINV(x) asm volatile("" : "+v"(x))

#define TWO_LOG2E 2.8853900817779268f

DEV void lds_barrier() {
    // LDS-only barrier: do NOT drain vmcnt (global stores/loads keep flying).
    asm volatile("s_waitcnt lgkmcnt(0)\n\ts_barrier" ::: "memory");
}

DEV unsigned short f2bf(float f) {
    union { float f; unsigned u; } v; v.f = f;
    unsigned r = (v.u + 0x7fffu + ((v.u >> 16) & 1u)) >> 16;
    return (unsigned short)r;
}

// ---------------------------------------------------------------------------
// packi8: one block (64 thr) per W row j. Row absmax -> per-row scale;
// quantize to i8 in A-frag layout for mfma_i32_16x16x64_i8.
// sc2[j] = mx_j / 127^2 * 2*log2(e)  (dequant folded into exp2 argument).
// ---------------------------------------------------------------------------
__global__ __launch_bounds__(64) void packi8_kernel(
    const float* __restrict__ W, signed char* __restrict__ Wq,
    float* __restrict__ sc2)
{
    const int j = blockIdx.x;            // 0..511
    const int t = threadIdx.x;           // 0..63
    const float* row = W + (size_t)j * 512;

    float4 a = *(const float4*)(row + t * 8);
    float4 b = *(const float4*)(row + t * 8 + 4);
    float m = fmaxf(fmaxf(fabsf(a.x), fabsf(a.y)), fmaxf(fabsf(a.z), fabsf(a.w)));
    m = fmaxf(m, fmaxf(fmaxf(fabsf(b.x), fabsf(b.y)), fmaxf(fabsf(b.z), fabsf(b.w))));
    #pragma unroll
    for (int off = 32; off; off >>= 1) m = fmaxf(m, __shfl_down(m, off, 64));
    m = __shfl(m, 0, 64);
    if (t == 0) sc2[j] = m * (1.0f / (127.f * 127.f)) * TWO_LOG2E;

    if (t < 32) {
        const int kt = t >> 2, lq = t & 3;
        const int jtg = j >> 4, lm = j & 15;
        const float r = 127.f / m;
        int w4[4];
        #pragma unroll
        for (int w = 0; w < 4; ++w) {
            int v = 0;
            #pragma unroll
            for (int e = 0; e < 4; ++e) {
                int q = __float2int_rn(row[kt * 64 + lq * 16 + w * 4 + e] * r);
                v |= (q & 255) << (8 * e);
            }
            w4[w] = v;
        }
        i32x4 pk; pk[0] = w4[0]; pk[1] = w4[1]; pk[2] = w4[2]; pk[3] = w4[3];
        *(i32x4*)(Wq + ((size_t)((jtg * 8 + kt) * 64 + lq * 16 + lm)) * 16) = pk;
    }
}

// ---------------------------------------------------------------------------
// proj: out[m=t*128+b][n] = bf16( (A[m][:]·W[n][:] + b1[n]+b2[n]) * oscale )
// oscale = 2*log2(e): rec consumes xp only inside exp2 arguments.
// ---------------------------------------------------------------------------
template <int K, int MODE>
__global__ __launch_bounds__(256, 2) void proj_kernel(
    const void* __restrict__ Aptr, const float* __restrict__ W,
    const float* __restrict__ b1, const float* __restrict__ b2,
    unsigned short* __restrict__ out, float oscale)
{
    constexpr int LDA = 40;
    __shared__ unsigned short As[128 * LDA];
    __shared__ unsigned short Ws[64 * LDA];

    const int tid  = threadIdx.x;
    const int lane = tid & 63, wave = tid >> 6;
    const int lm   = lane & 15, lq = lane >> 4;
    const int nbase = blockIdx.x * 64;
    const int mtile = blockIdx.y;
    const int mbase = mtile * 128;

    floatx4 acc[2][4] = {};

    const int ar = tid >> 1, ak = (tid & 1) * 16;
    const int wr = tid >> 2, wk = (tid & 3) * 8;

    for (int k0 = 0; k0 < K; k0 += 32) {
        if (MODE == 0) {
            const float* x   = (const float*)Aptr;
            const float* src = x + ((size_t)ar * 512 + mtile) * 128 + (k0 + ak);
            float4 f0 = *(const float4*)(src + 0);
            float4 f1 = *(const float4*)(src + 4);
            float4 f2 = *(const float4*)(src + 8);
            float4 f3 = *(const float4*)(src + 12);
            unsigned short* d = As + ar * LDA + ak;
            d[0]=f2bf(f0.x); d[1]=f2bf(f0.y); d[2]=f2bf(f0.z); d[3]=f2bf(f0.w);
            d[4]=f2bf(f1.x); d[5]=f2bf(f1.y); d[6]=f2bf(f1.z); d[7]=f2bf(f1.w);
            d[8]=f2bf(f2.x); d[9]=f2bf(f2.y); d[10]=f2bf(f2.z); d[11]=f2bf(f2.w);
            d[12]=f2bf(f3.x); d[13]=f2bf(f3.y); d[14]=f2bf(f3.z); d[15]=f2bf(f3.w);
        } else {
            const unsigned short* h =
                (const unsigned short*)Aptr + (size_t)(mbase + ar) * K + k0 + ak;
            short8 v0 = *(const short8*)(h);
            short8 v1 = *(const short8*)(h + 8);
            *(short8*)(As + ar * LDA + ak)     = v0;
            *(short8*)(As + ar * LDA + ak + 8) = v1;
        }
        {
            const float* src = W + (size_t)(nbase + wr) * K + k0 + wk;
            float4 f0 = *(const float4*)(src);
            float4 f1 = *(const float4*)(src + 4);
            unsigned short* d = Ws + wr * LDA + wk;
            d[0]=f2bf(f0.x); d[1]=f2bf(f0.y); d[2]=f2bf(f0.z); d[3]=f2bf(f0.w);
            d[4]=f2bf(f1.x); d[5]=f2bf(f1.y); d[6]=f2bf(f1.z); d[7]=f2bf(f1.w);
        }
        __syncthreads();

        short8 af0 = *(const short8*)(As + (wave * 32 +  0 + lm) * LDA + lq * 8);
        short8 af1 = *(const short8*)(As + (wave * 32 + 16 + lm) * LDA + lq * 8);
        #pragma unroll
        for (int nt = 0; nt < 4; ++nt) {
            short8 bf = *(const short8*)(Ws + (nt * 16 + lm) * LDA + lq * 8);
            acc[0][nt] = __builtin_amdgcn_mfma_f32_16x16x32_bf16(af0, bf, acc[0][nt], 0, 0, 0);
            acc[1][nt] = __builtin_amdgcn_mfma_f32_16x16x32_bf16(af1, bf, acc[1][nt], 0, 0, 0);
        }
        __syncthreads();
    }

    #pragma unroll
    for (int nt = 0; nt < 4; ++nt) {
        const int n = nbase + nt * 16 + lm;
        const float bias = b1[n] + b2[n];
        #pragma unroll
        for (int mt = 0; mt < 2; ++mt) {
            const int mrow = mbase + wave * 32 + mt * 16 + lq * 4;
            #pragma unroll
            for (int r = 0; r < 4; ++r)
                out[(size_t)(mrow + r) * 512 + n] = f2bf((acc[mt][nt][r] + bias) * oscale);
        }
    }
}

// ---------------------------------------------------------------------------
// rec11: 8 WGs x 512 thr (8 waves, 2/SIMD). WG bg owns batches [bg*16,+16),
// full H=512; wave owns 4 j-tiles. W_hh(i8) slice in 128 AGPRs per wave.
// h state: i8 LDS [2][16 b][512 j], 16B-granule swizzle g' = g ^ lm.
// j-pipelined: MFMA(j) ; epi(j-1). xv prefetched one full step ahead.
// 2 waves/SIMD: the co-resident wave covers ds_read / MFMA-chain / trans
// latency that stalled the 1-wave/SIMD R10 version ~50% of each step.
// MODE 0: store h_t bf16 to hs_out (in-place over xp). MODE 1: t=511 -> h_last.
// ---------------------------------------------------------------------------

#define MFMA_J(JJ, BFR)                                                        \
  {                                                                            \
    acc[JJ] = __builtin_amdgcn_mfma_i32_16x16x64_i8(wa[JJ][0], BFR[0], z4, 0, 0, 0); \
    _Pragma("unroll")                                                          \
    for (int kt = 1; kt < 8; ++kt)                                             \
      acc[JJ] = __builtin_amdgcn_mfma_i32_16x16x64_i8(wa[JJ][kt], BFR[kt], acc[JJ], 0, 0, 0); \
  }

#define EPI_J(JJ, XVROW, HWBUF, TCUR)                                          \
  {                                                                            \
    const int jtg = wave * 4 + (JJ);                                           \
    float x0 = __uint_as_float(__builtin_amdgcn_perm(XVROW[JJ].x, 0u, 0x05040c0cu)); \
    float x1 = __uint_as_float(__builtin_amdgcn_perm(XVROW[JJ].x, 0u, 0x07060c0cu)); \
    float x2 = __uint_as_float(__builtin_amdgcn_perm(XVROW[JJ].y, 0u, 0x05040c0cu)); \
    float x3 = __uint_as_float(__builtin_amdgcn_perm(XVROW[JJ].y, 0u, 0x07060c0cu)); \
    float e0 = __builtin_amdgcn_exp2f(fmaf((float)acc[JJ][0], sc[JJ][0], x0));  \
    float e1 = __builtin_amdgcn_exp2f(fmaf((float)acc[JJ][1], sc[JJ][1], x1));  \
    float e2 = __builtin_amdgcn_exp2f(fmaf((float)acc[JJ][2], sc[JJ][2], x2));  \
    float e3 = __builtin_amdgcn_exp2f(fmaf((float)acc[JJ][3], sc[JJ][3], x3));  \
    float q0 = fmaf(-2.f, __builtin_amdgcn_rcpf(e0 + 1.f), 1.f);                \
    float q1 = fmaf(-2.f, __builtin_amdgcn_rcpf(e1 + 1.f), 1.f);                \
    float q2 = fmaf(-2.f, __builtin_amdgcn_rcpf(e2 + 1.f), 1.f);                \
    float q3 = fmaf(-2.f, __builtin_amdgcn_rcpf(e3 + 1.f), 1.f);                \
    unsigned m0 = __float_as_uint(fmaf(q0, 127.f, 12582912.f));                 \
    unsigned m1 = __float_as_uint(fmaf(q1, 127.f, 12582912.f));                 \
    unsigned m2 = __float_as_uint(fmaf(q2, 127.f, 12582912.f));                 \
    unsigned m3 = __float_as_uint(fmaf(q3, 127.f, 12582912.f));                 \
    unsigned lo = __builtin_amdgcn_perm(m1, m0, 0x00000400u);                   \
    unsigned hi = __builtin_amdgcn_perm(m3, m2, 0x00000400u);                   \
    unsigned qb = __builtin_amdgcn_perm(hi, lo, 0x05040100u);                   \
    *(unsigned*)((HWBUF) + lm * 512 + ((jtg ^ lm) << 4) + lq * 4) = qb;         \
    if (MODE == 0) {                                                            \
      uint2 st;                                                                 \
      st.x = __builtin_amdgcn_perm(__float_as_uint(q1), __float_as_uint(q0), 0x07060302u); \
      st.y = __builtin_amdgcn_perm(__float_as_uint(q3), __float_as_uint(q2), 0x07060302u); \
      *(uint2*)(hst + (JJ) * 16) = st;                                          \
    } else if ((TCUR) == 511) {                                                 \
      float4 o; o.x = q0; o.y = q1; o.z = q2; o.w = q3;                         \
      *(float4*)(h_last + (size_t)bb * 512 + jtg * 16 + lq * 4) = o;            \
    }                                                                           \
  }

#define REC_STEP(P, TCUR)                                                      \
  {                                                                            \
    i32x4 bfr[8];                                                              \
    _Pragma("unroll")                                                          \
    for (int kt = 0; kt < 8; ++kt)                                             \
      bfr[kt] = *(const i32x4*)(&h2[P][0] + lm * 512 + ((((kt << 2) + lq)) ^ lm) * 16); \
    if ((TCUR) < 511) {                                                        \
      _Pragma("unroll")                                                        \
      for (int j = 0; j < 4; ++j)                                              \
        xv[(P) ^ 1][j] = *(const uint2*)(xpt + j * 16);                        \
      xpt += 65536;                                                            \
    }                                                                          \
    MFMA_J(0, bfr);                                                            \
    _Pragma("unroll")                                                          \
    for (int j = 1; j < 4; ++j) {                                              \
      MFMA_J(j, bfr);                                                          \
      EPI_J(j - 1, xv[P], &h2[(P) ^ 1][0], TCUR);                              \
    }                                                                          \
    EPI_J(3, xv[P], &h2[(P) ^ 1][0], TCUR);                                    \
    if (MODE == 0) hst += 65536;                                               \
    lds_barrier();                                                             \
  }

template <int MODE>
__global__ __launch_bounds__(512, 2) void rec11_kernel(
    const signed char* __restrict__ Wq,   // [32 jtg][8 kt][64 lane][16] i8
    const float* __restrict__ sc2,        // [512] row scale * 2log2e / 127^2
    const unsigned short* xp,             // [S][B][H] bf16 SCALED (aliases hs_out)
    unsigned short* hs_out,               // [S][B][H] bf16
    float* __restrict__ h_last)           // [B][H] fp32
{
    __shared__ unsigned char h2[2][16 * 512];   // 16 KB

    const int tid  = threadIdx.x;
    const int lane = tid & 63;
    const int wave = tid >> 6;              // 0..7
    const int lm   = lane & 15, lq = lane >> 4;
    const int bg   = blockIdx.x;
    const int bb   = bg * 16 + lm;

    // ---- W slice in AGPRs: 4 jtg x 8 kt x int4 = 128 AGPRs per wave ----
    i32x4 wa[4][8];
    #pragma unroll
    for (int j = 0; j < 4; ++j) {
        const int jtg = wave * 4 + j;
        #pragma unroll
        for (int kt = 0; kt < 8; ++kt)
            wa[j][kt] = *(const i32x4*)(Wq + ((size_t)((jtg * 8 + kt) * 64 + lane)) * 16);
    }
    #pragma unroll
    for (int j = 0; j < 4; ++j)
        #pragma unroll
        for (int kt = 0; kt < 8; ++kt)
            PINA(wa[j][kt]);

    // ---- per-lane fused dequant scales, pinned ----
    f32x4 sc[4];
    #pragma unroll
    for (int j = 0; j < 4; ++j)
        sc[j] = *(const f32x4*)(sc2 + (wave * 4 + j) * 16 + lq * 4);
    #pragma unroll
    for (int j = 0; j < 4; ++j) PINV(sc[j]);

    // ---- zero h buffers ----
    for (int i = tid; i < 4096; i += 512) ((int*)h2)[i] = 0;
    __syncthreads();

    // per-thread streaming pointers (row stride 128*512 elems per step)
    const unsigned short* xpt = xp + (size_t)bb * 512 + wave * 64 + lq * 4;
    unsigned short*       hst = hs_out + (size_t)bb * 512 + wave * 64 + lq * 4;

    uint2 xv[2][4];
    i32x4 acc[4];
    const i32x4 z4 = {0, 0, 0, 0};

    // ---- prologue: xv[0] = row 0 ----
    #pragma unroll
    for (int j = 0; j < 4; ++j) xv[0][j] = *(const uint2*)(xpt + j * 16);
    xpt += 65536;

    for (int t = 0; t < 512; t += 2) {
        REC_STEP(0, t);
        REC_STEP(1, t + 1);
    }
}

// ---------------------------------------------------------------------------
// head: logits[b][c] = h_last[b][:]·W_out[c][:] + b_out[c]; log_softmax rows.
// ---------------------------------------------------------------------------
__global__ __launch_bounds__(256, 2) void head_kernel(
    const float* __restrict__ hl, const float* __restrict__ Wout,
    const float* __restrict__ bout, float* __restrict__ out)
{
    __shared__ float hrow[512];
    __shared__ float lg[1000];
    __shared__ float red[8];
    const int b = blockIdx.x, tid = threadIdx.x;

    hrow[tid]       = hl[(size_t)b * 512 + tid];
    hrow[tid + 256] = hl[(size_t)b * 512 + 256 + tid];
    __syncthreads();

    float lmax = -1e30f;
    for (int c = tid; c < 1000; c += 256) {
        const float4* w4 = (const float4*)(Wout + (size_t)c * 512);
        float a0 = 0.f, a1 = 0.f, a2 = 0.f, a3 = 0.f;
        #pragma unroll 4
        for (int k = 0; k < 128; ++k) {
            float4 w = w4[k];
            a0 += hrow[4 * k + 0] * w.x;
            a1 += hrow[4 * k + 1] * w.y;
            a2 += hrow[4 * k + 2] * w.z;
            a3 += hrow[4 * k + 3] * w.w;
        }
        float acc = bout[c] + (a0 + a1) + (a2 + a3);
        lg[c] = acc;
        lmax = fmaxf(lmax, acc);
    }
    #pragma unroll
    for (int off = 32; off; off >>= 1) lmax = fmaxf(lmax, __shfl_down(lmax, off, 64));
    if ((tid & 63) == 0) red[tid >> 6] = lmax;
    __syncthreads();
    if (tid == 0) red[4] = fmaxf(fmaxf(red[0], red[1]), fmaxf(red[2], red[3]));
    __syncthreads();
    const float M = red[4];

    float lsum = 0.f;
    for (int c = tid; c < 1000; c += 256) lsum += __expf(lg[c] - M);
    #pragma unroll
    for (int off = 32; off; off >>= 1) lsum += __shfl_down(lsum, off, 64);
    __syncthreads();
    if ((tid & 63) == 0) red[tid >> 6] = lsum;
    __syncthreads();
    if (tid == 0) red[5] = M + __logf(red[0] + red[1] + red[2] + red[3]);
    __syncthreads();
    const float lse = red[5];

    for (int c = tid; c < 1000; c += 256)
        out[(size_t)b * 1000 + c] = lg[c] - lse;
}

// ---------------------------------------------------------------------------
extern "C" void kernel_launch(void* const* d_in, const int* in_sizes, int n_in,
                              void* d_out, int out_size, void* d_ws, size_t ws_size,
                              hipStream_t stream)
{
    const float* x    = (const float*)d_in[0];
    const float* Wih0 = (const float*)d_in[1];
    const float* Whh0 = (const float*)d_in[2];
    const float* bih0 = (const float*)d_in[3];
    const float* bhh0 = (const float*)d_in[4];
    const float* Wih1 = (const float*)d_in[5];
    const float* Whh1 = (const float*)d_in[6];
    const float* bih1 = (const float*)d_in[7];
    const float* bhh1 = (const float*)d_in[8];
    const float* Wout = (const float*)d_in[9];
    const float* bout = (const float*)d_in[10];
    float* out = (float*)d_out;

    char* ws = (char*)d_ws;
    unsigned short* bufA = (unsigned short*)ws;                              // 64 MB
    unsigned short* bufB = (unsigned short*)(ws + (size_t)64 * 1024 * 1024);
    signed char* Wq0 = (signed char*)bufB;                                   // 256 KB (dead after rec0)
    float*       sc0 = (float*)((char*)bufB + 262144);                       // 2 KB
    signed char* Wq1 = (signed char*)bufA;                                   // 256 KB (after proj1 consumed bufA)
    float*       sc1 = (float*)(ws + 262144);                                // 2 KB
    float*     hlast = (float*)(ws + (size_t)1 * 1024 * 1024);               // 256 KB

    const dim3 pgrid(8, 512);

    packi8_kernel<<<512, 64, 0, stream>>>(Whh0, Wq0, sc0);
    proj_kernel<128, 0><<<pgrid, 256, 0, stream>>>((const void*)x, Wih0, bih0, bhh0, bufA, TWO_LOG2E);
    rec11_kernel<0><<<8, 512, 0, stream>>>(Wq0, sc0, bufA, bufA, hlast);

    proj_kernel<512, 1><<<pgrid, 256, 0, stream>>>((const void*)bufA, Wih1, bih1, bhh1, bufB, TWO_LOG2E);
    packi8_kernel<<<512, 64, 0, stream>>>(Whh1, Wq1, sc1);
    rec11_kernel<1><<<8, 512, 0, stream>>>(Wq1, sc1, bufB, bufB, hlast);

    head_kernel<<<128, 256, 0, stream>>>(hlast, Wout, bout, out);
}

// Round 2
// 1658.432 us; speedup vs baseline: 1.2053x; 1.1311x over previous
//
#include <hip/hip_runtime.h>

// ============================================================================
// 2-layer tanh RNN (B=128,S=512,IN=128,H=512) + linear head (C=1000) + logsoftmax
//
// Round-12: DVFS experiment. R10/R11 counters are self-consistent with the
//   shader clock sitting at ~800 MHz (8/256 CUs busy -> low DPM level):
//   VALU-issue count / VALUBusy gives step ~1300 cy = exactly the i8 matrix
//   pipe floor (256 MFMA/CU/step x 5.1 cy), and MfmaUtil 25% matches
//   MFMA-issue/step. I.e. the kernel is at the per-CU MFMA roofline and wall
//   time is (cycles)/(low clock). The 31-ms rocprof replay outlier (deep-idle
//   DPM) supports clock variability.
//   Fix attempt: batch-replication to 64 WGs x 2 real batches (lanes lm>=2
//   compute replicas of batches 0/1; global stores masked to lm<2). Per-CU
//   work, LDS traffic, and numerics for real batches are bit-identical to
//   R11 -- only the number of busy CUs changes (8 -> 64), to pull the DPM
//   governor up. If the clock theory is right: rec 860 -> ~300-500 us.
//   If null: step is chain-bound at fixed clock -> next round j-splits.
//
// ws layout: bufA = ws (64 MB): xp0/hs0 in place; later Wq1 head + hlast @
//            +1MB. bufB = ws+64MB: Wq0/sc0 head (dead after rec0), later xp1.
// ============================================================================

using short8  = __attribute__((ext_vector_type(8))) short;
using floatx4 = __attribute__((ext_vector_type(4))) float;
using i32x4   = __attribute__((ext_vector_type(4))) int;
using f32x4   = __attribute__((ext_vector_type(4))) float;

#define DEV static __device__ __forceinline__
#define PINA(x) asm volatile("" : "+a"(x))
#define PINV(x) asm volatile("" : "+v"(x))

#define TWO_LOG2E 2.8853900817779268f

DEV void lds_barrier() {
    // LDS-only barrier: do NOT drain vmcnt (global stores/loads keep flying).
    asm volatile("s_waitcnt lgkmcnt(0)\n\ts_barrier" ::: "memory");
}

DEV unsigned short f2bf(float f) {
    union { float f; unsigned u; } v; v.f = f;
    unsigned r = (v.u + 0x7fffu + ((v.u >> 16) & 1u)) >> 16;
    return (unsigned short)r;
}

// ---------------------------------------------------------------------------
// packi8: one block (64 thr) per W row j. Row absmax -> per-row scale;
// quantize to i8 in A-frag layout for mfma_i32_16x16x64_i8.
// sc2[j] = mx_j / 127^2 * 2*log2(e)  (dequant folded into exp2 argument).
// ---------------------------------------------------------------------------
__global__ __launch_bounds__(64) void packi8_kernel(
    const float* __restrict__ W, signed char* __restrict__ Wq,
    float* __restrict__ sc2)
{
    const int j = blockIdx.x;            // 0..511
    const int t = threadIdx.x;           // 0..63
    const float* row = W + (size_t)j * 512;

    float4 a = *(const float4*)(row + t * 8);
    float4 b = *(const float4*)(row + t * 8 + 4);
    float m = fmaxf(fmaxf(fabsf(a.x), fabsf(a.y)), fmaxf(fabsf(a.z), fabsf(a.w)));
    m = fmaxf(m, fmaxf(fmaxf(fabsf(b.x), fabsf(b.y)), fmaxf(fabsf(b.z), fabsf(b.w))));
    #pragma unroll
    for (int off = 32; off; off >>= 1) m = fmaxf(m, __shfl_down(m, off, 64));
    m = __shfl(m, 0, 64);
    if (t == 0) sc2[j] = m * (1.0f / (127.f * 127.f)) * TWO_LOG2E;

    if (t < 32) {
        const int kt = t >> 2, lq = t & 3;
        const int jtg = j >> 4, lm = j & 15;
        const float r = 127.f / m;
        int w4[4];
        #pragma unroll
        for (int w = 0; w < 4; ++w) {
            int v = 0;
            #pragma unroll
            for (int e = 0; e < 4; ++e) {
                int q = __float2int_rn(row[kt * 64 + lq * 16 + w * 4 + e] * r);
                v |= (q & 255) << (8 * e);
            }
            w4[w] = v;
        }
        i32x4 pk; pk[0] = w4[0]; pk[1] = w4[1]; pk[2] = w4[2]; pk[3] = w4[3];
        *(i32x4*)(Wq + ((size_t)((jtg * 8 + kt) * 64 + lq * 16 + lm)) * 16) = pk;
    }
}

// ---------------------------------------------------------------------------
// proj: out[m=t*128+b][n] = bf16( (A[m][:]·W[n][:] + b1[n]+b2[n]) * oscale )
// oscale = 2*log2(e): rec consumes xp only inside exp2 arguments.
// ---------------------------------------------------------------------------
template <int K, int MODE>
__global__ __launch_bounds__(256, 2) void proj_kernel(
    const void* __restrict__ Aptr, const float* __restrict__ W,
    const float* __restrict__ b1, const float* __restrict__ b2,
    unsigned short* __restrict__ out, float oscale)
{
    constexpr int LDA = 40;
    __shared__ unsigned short As[128 * LDA];
    __shared__ unsigned short Ws[64 * LDA];

    const int tid  = threadIdx.x;
    const int lane = tid & 63, wave = tid >> 6;
    const int lm   = lane & 15, lq = lane >> 4;
    const int nbase = blockIdx.x * 64;
    const int mtile = blockIdx.y;
    const int mbase = mtile * 128;

    floatx4 acc[2][4] = {};

    const int ar = tid >> 1, ak = (tid & 1) * 16;
    const int wr = tid >> 2, wk = (tid & 3) * 8;

    for (int k0 = 0; k0 < K; k0 += 32) {
        if (MODE == 0) {
            const float* x   = (const float*)Aptr;
            const float* src = x + ((size_t)ar * 512 + mtile) * 128 + (k0 + ak);
            float4 f0 = *(const float4*)(src + 0);
            float4 f1 = *(const float4*)(src + 4);
            float4 f2 = *(const float4*)(src + 8);
            float4 f3 = *(const float4*)(src + 12);
            unsigned short* d = As + ar * LDA + ak;
            d[0]=f2bf(f0.x); d[1]=f2bf(f0.y); d[2]=f2bf(f0.z); d[3]=f2bf(f0.w);
            d[4]=f2bf(f1.x); d[5]=f2bf(f1.y); d[6]=f2bf(f1.z); d[7]=f2bf(f1.w);
            d[8]=f2bf(f2.x); d[9]=f2bf(f2.y); d[10]=f2bf(f2.z); d[11]=f2bf(f2.w);
            d[12]=f2bf(f3.x); d[13]=f2bf(f3.y); d[14]=f2bf(f3.z); d[15]=f2bf(f3.w);
        } else {
            const unsigned short* h =
                (const unsigned short*)Aptr + (size_t)(mbase + ar) * K + k0 + ak;
            short8 v0 = *(const short8*)(h);
            short8 v1 = *(const short8*)(h + 8);
            *(short8*)(As + ar * LDA + ak)     = v0;
            *(short8*)(As + ar * LDA + ak + 8) = v1;
        }
        {
            const float* src = W + (size_t)(nbase + wr) * K + k0 + wk;
            float4 f0 = *(const float4*)(src);
            float4 f1 = *(const float4*)(src + 4);
            unsigned short* d = Ws + wr * LDA + wk;
            d[0]=f2bf(f0.x); d[1]=f2bf(f0.y); d[2]=f2bf(f0.z); d[3]=f2bf(f0.w);
            d[4]=f2bf(f1.x); d[5]=f2bf(f1.y); d[6]=f2bf(f1.z); d[7]=f2bf(f1.w);
        }
        __syncthreads();

        short8 af0 = *(const short8*)(As + (wave * 32 +  0 + lm) * LDA + lq * 8);
        short8 af1 = *(const short8*)(As + (wave * 32 + 16 + lm) * LDA + lq * 8);
        #pragma unroll
        for (int nt = 0; nt < 4; ++nt) {
            short8 bf = *(const short8*)(Ws + (nt * 16 + lm) * LDA + lq * 8);
            acc[0][nt] = __builtin_amdgcn_mfma_f32_16x16x32_bf16(af0, bf, acc[0][nt], 0, 0, 0);
            acc[1][nt] = __builtin_amdgcn_mfma_f32_16x16x32_bf16(af1, bf, acc[1][nt], 0, 0, 0);
        }
        __syncthreads();
    }

    #pragma unroll
    for (int nt = 0; nt < 4; ++nt) {
        const int n = nbase + nt * 16 + lm;
        const float bias = b1[n] + b2[n];
        #pragma unroll
        for (int mt = 0; mt < 2; ++mt) {
            const int mrow = mbase + wave * 32 + mt * 16 + lq * 4;
            #pragma unroll
            for (int r = 0; r < 4; ++r)
                out[(size_t)(mrow + r) * 512 + n] = f2bf((acc[mt][nt][r] + bias) * oscale);
        }
    }
}

// ---------------------------------------------------------------------------
// rec12: 64 WGs x 512 thr (8 waves, 2/SIMD). WG bg owns REAL batches
// {bg*2, bg*2+1}; lanes lm>=2 compute replicas (junk-free: they mirror
// batches 0/1 of the WG), global stores masked to lm<2. Per-CU work is
// identical to R11; only the busy-CU count changes (8 -> 64) to raise the
// DPM clock. Wave owns 4 j-tiles; W_hh(i8) slice in 128 AGPRs per wave.
// h state: i8 LDS [2][16 b][512 j], 16B-granule swizzle g' = g ^ lm.
// j-pipelined: MFMA(j) ; epi(j-1). xv prefetched one full step ahead.
// MODE 0: store h_t bf16 to hs_out (in-place over xp). MODE 1: t=511 -> h_last.
// ---------------------------------------------------------------------------

#define MFMA_J(JJ, BFR)                                                        \
  {                                                                            \
    acc[JJ] = __builtin_amdgcn_mfma_i32_16x16x64_i8(wa[JJ][0], BFR[0], z4, 0, 0, 0); \
    _Pragma("unroll")                                                          \
    for (int kt = 1; kt < 8; ++kt)                                             \
      acc[JJ] = __builtin_amdgcn_mfma_i32_16x16x64_i8(wa[JJ][kt], BFR[kt], acc[JJ], 0, 0, 0); \
  }

#define EPI_J(JJ, XVROW, HWBUF, TCUR)                                          \
  {                                                                            \
    const int jtg = wave * 4 + (JJ);                                           \
    float x0 = __uint_as_float(__builtin_amdgcn_perm(XVROW[JJ].x, 0u, 0x05040c0cu)); \
    float x1 = __uint_as_float(__builtin_amdgcn_perm(XVROW[JJ].x, 0u, 0x07060c0cu)); \
    float x2 = __uint_as_float(__builtin_amdgcn_perm(XVROW[JJ].y, 0u, 0x05040c0cu)); \
    float x3 = __uint_as_float(__builtin_amdgcn_perm(XVROW[JJ].y, 0u, 0x07060c0cu)); \
    float e0 = __builtin_amdgcn_exp2f(fmaf((float)acc[JJ][0], sc[JJ][0], x0));  \
    float e1 = __builtin_amdgcn_exp2f(fmaf((float)acc[JJ][1], sc[JJ][1], x1));  \
    float e2 = __builtin_amdgcn_exp2f(fmaf((float)acc[JJ][2], sc[JJ][2], x2));  \
    float e3 = __builtin_amdgcn_exp2f(fmaf((float)acc[JJ][3], sc[JJ][3], x3));  \
    float q0 = fmaf(-2.f, __builtin_amdgcn_rcpf(e0 + 1.f), 1.f);                \
    float q1 = fmaf(-2.f, __builtin_amdgcn_rcpf(e1 + 1.f), 1.f);                \
    float q2 = fmaf(-2.f, __builtin_amdgcn_rcpf(e2 + 1.f), 1.f);                \
    float q3 = fmaf(-2.f, __builtin_amdgcn_rcpf(e3 + 1.f), 1.f);                \
    unsigned m0 = __float_as_uint(fmaf(q0, 127.f, 12582912.f));                 \
    unsigned m1 = __float_as_uint(fmaf(q1, 127.f, 12582912.f));                 \
    unsigned m2 = __float_as_uint(fmaf(q2, 127.f, 12582912.f));                 \
    unsigned m3 = __float_as_uint(fmaf(q3, 127.f, 12582912.f));                 \
    unsigned lo = __builtin_amdgcn_perm(m1, m0, 0x00000400u);                   \
    unsigned hi = __builtin_amdgcn_perm(m3, m2, 0x00000400u);                   \
    unsigned qb = __builtin_amdgcn_perm(hi, lo, 0x05040100u);                   \
    *(unsigned*)((HWBUF) + lm * 512 + ((jtg ^ lm) << 4) + lq * 4) = qb;         \
    if (MODE == 0) {                                                            \
      if (lm < 2) {                                                             \
        uint2 st;                                                               \
        st.x = __builtin_amdgcn_perm(__float_as_uint(q1), __float_as_uint(q0), 0x07060302u); \
        st.y = __builtin_amdgcn_perm(__float_as_uint(q3), __float_as_uint(q2), 0x07060302u); \
        *(uint2*)(hst + (JJ) * 16) = st;                                        \
      }                                                                         \
    } else if ((TCUR) == 511) {                                                 \
      if (lm < 2) {                                                             \
        float4 o; o.x = q0; o.y = q1; o.z = q2; o.w = q3;                       \
        *(float4*)(h_last + (size_t)bb * 512 + jtg * 16 + lq * 4) = o;          \
      }                                                                         \
    }                                                                           \
  }

#define REC_STEP(P, TCUR)                                                      \
  {                                                                            \
    i32x4 bfr[8];                                                              \
    _Pragma("unroll")                                                          \
    for (int kt = 0; kt < 8; ++kt)                                             \
      bfr[kt] = *(const i32x4*)(&h2[P][0] + lm * 512 + ((((kt << 2) + lq)) ^ lm) * 16); \
    if ((TCUR) < 511) {                                                        \
      _Pragma("unroll")                                                        \
      for (int j = 0; j < 4; ++j)                                              \
        xv[(P) ^ 1][j] = *(const uint2*)(xpt + j * 16);                        \
      xpt += 65536;                                                            \
    }                                                                          \
    MFMA_J(0, bfr);                                                            \
    _Pragma("unroll")                                                          \
    for (int j = 1; j < 4; ++j) {                                              \
      MFMA_J(j, bfr);                                                          \
      EPI_J(j - 1, xv[P], &h2[(P) ^ 1][0], TCUR);                              \
    }                                                                          \
    EPI_J(3, xv[P], &h2[(P) ^ 1][0], TCUR);                                    \
    if (MODE == 0) hst += 65536;                                               \
    lds_barrier();                                                             \
  }

template <int MODE>
__global__ __launch_bounds__(512, 2) void rec12_kernel(
    const signed char* __restrict__ Wq,   // [32 jtg][8 kt][64 lane][16] i8
    const float* __restrict__ sc2,        // [512] row scale * 2log2e / 127^2
    const unsigned short* xp,             // [S][B][H] bf16 SCALED (aliases hs_out)
    unsigned short* hs_out,               // [S][B][H] bf16
    float* __restrict__ h_last)           // [B][H] fp32
{
    __shared__ unsigned char h2[2][16 * 512];   // 16 KB

    const int tid  = threadIdx.x;
    const int lane = tid & 63;
    const int wave = tid >> 6;              // 0..7
    const int lm   = lane & 15, lq = lane >> 4;
    const int bg   = blockIdx.x;            // 0..63
    const int bb   = bg * 2 + (lm & 1);     // replicate 2 real batches across 16 rows

    // ---- W slice in AGPRs: 4 jtg x 8 kt x int4 = 128 AGPRs per wave ----
    i32x4 wa[4][8];
    #pragma unroll
    for (int j = 0; j < 4; ++j) {
        const int jtg = wave * 4 + j;
        #pragma unroll
        for (int kt = 0; kt < 8; ++kt)
            wa[j][kt] = *(const i32x4*)(Wq + ((size_t)((jtg * 8 + kt) * 64 + lane)) * 16);
    }
    #pragma unroll
    for (int j = 0; j < 4; ++j)
        #pragma unroll
        for (int kt = 0; kt < 8; ++kt)
            PINA(wa[j][kt]);

    // ---- per-lane fused dequant scales, pinned ----
    f32x4 sc[4];
    #pragma unroll
    for (int j = 0; j < 4; ++j)
        sc[j] = *(const f32x4*)(sc2 + (wave * 4 + j) * 16 + lq * 4);
    #pragma unroll
    for (int j = 0; j < 4; ++j) PINV(sc[j]);

    // ---- zero h buffers ----
    for (int i = tid; i < 4096; i += 512) ((int*)h2)[i] = 0;
    __syncthreads();

    // per-thread streaming pointers (row stride 128*512 elems per step)
    const unsigned short* xpt = xp + (size_t)bb * 512 + wave * 64 + lq * 4;
    unsigned short*       hst = hs_out + (size_t)bb * 512 + wave * 64 + lq * 4;

    uint2 xv[2][4];
    i32x4 acc[4];
    const i32x4 z4 = {0, 0, 0, 0};

    // ---- prologue: xv[0] = row 0 ----
    #pragma unroll
    for (int j = 0; j < 4; ++j) xv[0][j] = *(const uint2*)(xpt + j * 16);
    xpt += 65536;

    for (int t = 0; t < 512; t += 2) {
        REC_STEP(0, t);
        REC_STEP(1, t + 1);
    }
}

// ---------------------------------------------------------------------------
// head: logits[b][c] = h_last[b][:]·W_out[c][:] + b_out[c]; log_softmax rows.
// ---------------------------------------------------------------------------
__global__ __launch_bounds__(256, 2) void head_kernel(
    const float* __restrict__ hl, const float* __restrict__ Wout,
    const float* __restrict__ bout, float* __restrict__ out)
{
    __shared__ float hrow[512];
    __shared__ float lg[1000];
    __shared__ float red[8];
    const int b = blockIdx.x, tid = threadIdx.x;

    hrow[tid]       = hl[(size_t)b * 512 + tid];
    hrow[tid + 256] = hl[(size_t)b * 512 + 256 + tid];
    __syncthreads();

    float lmax = -1e30f;
    for (int c = tid; c < 1000; c += 256) {
        const float4* w4 = (const float4*)(Wout + (size_t)c * 512);
        float a0 = 0.f, a1 = 0.f, a2 = 0.f, a3 = 0.f;
        #pragma unroll 4
        for (int k = 0; k < 128; ++k) {
            float4 w = w4[k];
            a0 += hrow[4 * k + 0] * w.x;
            a1 += hrow[4 * k + 1] * w.y;
            a2 += hrow[4 * k + 2] * w.z;
            a3 += hrow[4 * k + 3] * w.w;
        }
        float acc = bout[c] + (a0 + a1) + (a2 + a3);
        lg[c] = acc;
        lmax = fmaxf(lmax, acc);
    }
    #pragma unroll
    for (int off = 32; off; off >>= 1) lmax = fmaxf(lmax, __shfl_down(lmax, off, 64));
    if ((tid & 63) == 0) red[tid >> 6] = lmax;
    __syncthreads();
    if (tid == 0) red[4] = fmaxf(fmaxf(red[0], red[1]), fmaxf(red[2], red[3]));
    __syncthreads();
    const float M = red[4];

    float lsum = 0.f;
    for (int c = tid; c < 1000; c += 256) lsum += __expf(lg[c] - M);
    #pragma unroll
    for (int off = 32; off; off >>= 1) lsum += __shfl_down(lsum, off, 64);
    __syncthreads();
    if ((tid & 63) == 0) red[tid >> 6] = lsum;
    __syncthreads();
    if (tid == 0) red[5] = M + __logf(red[0] + red[1] + red[2] + red[3]);
    __syncthreads();
    const float lse = red[5];

    for (int c = tid; c < 1000; c += 256)
        out[(size_t)b * 1000 + c] = lg[c] - lse;
}

// ---------------------------------------------------------------------------
extern "C" void kernel_launch(void* const* d_in, const int* in_sizes, int n_in,
                              void* d_out, int out_size, void* d_ws, size_t ws_size,
                              hipStream_t stream)
{
    const float* x    = (const float*)d_in[0];
    const float* Wih0 = (const float*)d_in[1];
    const float* Whh0 = (const float*)d_in[2];
    const float* bih0 = (const float*)d_in[3];
    const float* bhh0 = (const float*)d_in[4];
    const float* Wih1 = (const float*)d_in[5];
    const float* Whh1 = (const float*)d_in[6];
    const float* bih1 = (const float*)d_in[7];
    const float* bhh1 = (const float*)d_in[8];
    const float* Wout = (const float*)d_in[9];
    const float* bout = (const float*)d_in[10];
    float* out = (float*)d_out;

    char* ws = (char*)d_ws;
    unsigned short* bufA = (unsigned short*)ws;                              // 64 MB
    unsigned short* bufB = (unsigned short*)(ws + (size_t)64 * 1024 * 1024);
    signed char* Wq0 = (signed char*)bufB;                                   // 256 KB (dead after rec0)
    float*       sc0 = (float*)((char*)bufB + 262144);                       // 2 KB
    signed char* Wq1 = (signed char*)bufA;                                   // 256 KB (after proj1 consumed bufA)
    float*       sc1 = (float*)(ws + 262144);                                // 2 KB
    float*     hlast = (float*)(ws + (size_t)1 * 1024 * 1024);               // 256 KB

    const dim3 pgrid(8, 512);

    packi8_kernel<<<512, 64, 0, stream>>>(Whh0, Wq0, sc0);
    proj_kernel<128, 0><<<pgrid, 256, 0, stream>>>((const void*)x, Wih0, bih0, bhh0, bufA, TWO_LOG2E);
    rec12_kernel<0><<<64, 512, 0, stream>>>(Wq0, sc0, bufA, bufA, hlast);

    proj_kernel<512, 1><<<pgrid, 256, 0, stream>>>((const void*)bufA, Wih1, bih1, bhh1, bufB, TWO_LOG2E);
    packi8_kernel<<<512, 64, 0, stream>>>(Whh1, Wq1, sc1);
    rec12_kernel<1><<<64, 512, 0, stream>>>(Wq1, sc1, bufB, bufB, hlast);

    head_kernel<<<128, 256, 0, stream>>>(hlast, Wout, bout, out);
}

// Round 3
// 1512.455 us; speedup vs baseline: 1.3217x; 1.0965x over previous
//
#include <hip/hip_runtime.h>

// ============================================================================
// 2-layer tanh RNN (B=128,S=512,IN=128,H=512) + linear head (C=1000) + logsoftmax
//
// Round-13: two levers on the VALU-issue-bound rec loop.
//   R12 forensics: utils rose in proportion to speedup -> R11->R12 gain was
//   CYCLE reduction (stall), not clock. Step now ~3353 cy: MFMA 1030 (31%),
//   VALU-issue ~1930 (58%, the largest pipe), stall ~40%.
//   (1) xp stored as F16 (not bf16); EPI consumes it directly inside
//       v_fma_mix_f32 (op_sel selects f16 half) -> kills 4 perm-extracts per
//       EPI = 16 VALU insts/wave/step (~9% of VALU issue). hs_out stays bf16
//       so proj1's bf16-MFMA path is untouched. f16 precision >= bf16 here.
//   (2) 256 WGs: 2 WGs per real batch (bb = bg>>1), stores masked to even bg
//       and lm==0. All 256 CUs busy -> final DVFS probe point. Per-CU work
//       identical; if null, clock theory is dead.
//
// ws layout: bufA = ws (64 MB): xp0/hs0 in place; later Wq1 head + hlast @
//            +1MB. bufB = ws+64MB: Wq0/sc0 head (dead after rec0), later xp1.
// ============================================================================

using short8  = __attribute__((ext_vector_type(8))) short;
using floatx4 = __attribute__((ext_vector_type(4))) float;
using i32x4   = __attribute__((ext_vector_type(4))) int;
using f32x4   = __attribute__((ext_vector_type(4))) float;

#define DEV static __device__ __forceinline__
#define PINA(x) asm volatile("" : "+a"(x))
#define PINV(x) asm volatile("" : "+v"(x))

#define TWO_LOG2E 2.8853900817779268f

DEV void lds_barrier() {
    // LDS-only barrier: do NOT drain vmcnt (global stores/loads keep flying).
    asm volatile("s_waitcnt lgkmcnt(0)\n\ts_barrier" ::: "memory");
}

DEV unsigned short f2bf(float f) {
    union { float f; unsigned u; } v; v.f = f;
    unsigned r = (v.u + 0x7fffu + ((v.u >> 16) & 1u)) >> 16;
    return (unsigned short)r;
}

DEV unsigned short f2h(float f) {
    union { _Float16 h; unsigned short u; } c; c.h = (_Float16)f;
    return c.u;
}

// ---------------------------------------------------------------------------
// packi8: one block (64 thr) per W row j. Row absmax -> per-row scale;
// quantize to i8 in A-frag layout for mfma_i32_16x16x64_i8.
// sc2[j] = mx_j / 127^2 * 2*log2(e)  (dequant folded into exp2 argument).
// ---------------------------------------------------------------------------
__global__ __launch_bounds__(64) void packi8_kernel(
    const float* __restrict__ W, signed char* __restrict__ Wq,
    float* __restrict__ sc2)
{
    const int j = blockIdx.x;            // 0..511
    const int t = threadIdx.x;           // 0..63
    const float* row = W + (size_t)j * 512;

    float4 a = *(const float4*)(row + t * 8);
    float4 b = *(const float4*)(row + t * 8 + 4);
    float m = fmaxf(fmaxf(fabsf(a.x), fabsf(a.y)), fmaxf(fabsf(a.z), fabsf(a.w)));
    m = fmaxf(m, fmaxf(fmaxf(fabsf(b.x), fabsf(b.y)), fmaxf(fabsf(b.z), fabsf(b.w))));
    #pragma unroll
    for (int off = 32; off; off >>= 1) m = fmaxf(m, __shfl_down(m, off, 64));
    m = __shfl(m, 0, 64);
    if (t == 0) sc2[j] = m * (1.0f / (127.f * 127.f)) * TWO_LOG2E;

    if (t < 32) {
        const int kt = t >> 2, lq = t & 3;
        const int jtg = j >> 4, lm = j & 15;
        const float r = 127.f / m;
        int w4[4];
        #pragma unroll
        for (int w = 0; w < 4; ++w) {
            int v = 0;
            #pragma unroll
            for (int e = 0; e < 4; ++e) {
                int q = __float2int_rn(row[kt * 64 + lq * 16 + w * 4 + e] * r);
                v |= (q & 255) << (8 * e);
            }
            w4[w] = v;
        }
        i32x4 pk; pk[0] = w4[0]; pk[1] = w4[1]; pk[2] = w4[2]; pk[3] = w4[3];
        *(i32x4*)(Wq + ((size_t)((jtg * 8 + kt) * 64 + lq * 16 + lm)) * 16) = pk;
    }
}

// ---------------------------------------------------------------------------
// proj: out[m=t*128+b][n] = f16( (A[m][:]·W[n][:] + b1[n]+b2[n]) * oscale )
// oscale = 2*log2(e): rec consumes xp only inside exp2 arguments (via
// v_fma_mix_f32, so xp lives as packed f16 now).
// ---------------------------------------------------------------------------
template <int K, int MODE>
__global__ __launch_bounds__(256, 2) void proj_kernel(
    const void* __restrict__ Aptr, const float* __restrict__ W,
    const float* __restrict__ b1, const float* __restrict__ b2,
    unsigned short* __restrict__ out, float oscale)
{
    constexpr int LDA = 40;
    __shared__ unsigned short As[128 * LDA];
    __shared__ unsigned short Ws[64 * LDA];

    const int tid  = threadIdx.x;
    const int lane = tid & 63, wave = tid >> 6;
    const int lm   = lane & 15, lq = lane >> 4;
    const int nbase = blockIdx.x * 64;
    const int mtile = blockIdx.y;
    const int mbase = mtile * 128;

    floatx4 acc[2][4] = {};

    const int ar = tid >> 1, ak = (tid & 1) * 16;
    const int wr = tid >> 2, wk = (tid & 3) * 8;

    for (int k0 = 0; k0 < K; k0 += 32) {
        if (MODE == 0) {
            const float* x   = (const float*)Aptr;
            const float* src = x + ((size_t)ar * 512 + mtile) * 128 + (k0 + ak);
            float4 f0 = *(const float4*)(src + 0);
            float4 f1 = *(const float4*)(src + 4);
            float4 f2 = *(const float4*)(src + 8);
            float4 f3 = *(const float4*)(src + 12);
            unsigned short* d = As + ar * LDA + ak;
            d[0]=f2bf(f0.x); d[1]=f2bf(f0.y); d[2]=f2bf(f0.z); d[3]=f2bf(f0.w);
            d[4]=f2bf(f1.x); d[5]=f2bf(f1.y); d[6]=f2bf(f1.z); d[7]=f2bf(f1.w);
            d[8]=f2bf(f2.x); d[9]=f2bf(f2.y); d[10]=f2bf(f2.z); d[11]=f2bf(f2.w);
            d[12]=f2bf(f3.x); d[13]=f2bf(f3.y); d[14]=f2bf(f3.z); d[15]=f2bf(f3.w);
        } else {
            const unsigned short* h =
                (const unsigned short*)Aptr + (size_t)(mbase + ar) * K + k0 + ak;
            short8 v0 = *(const short8*)(h);
            short8 v1 = *(const short8*)(h + 8);
            *(short8*)(As + ar * LDA + ak)     = v0;
            *(short8*)(As + ar * LDA + ak + 8) = v1;
        }
        {
            const float* src = W + (size_t)(nbase + wr) * K + k0 + wk;
            float4 f0 = *(const float4*)(src);
            float4 f1 = *(const float4*)(src + 4);
            unsigned short* d = Ws + wr * LDA + wk;
            d[0]=f2bf(f0.x); d[1]=f2bf(f0.y); d[2]=f2bf(f0.z); d[3]=f2bf(f0.w);
            d[4]=f2bf(f1.x); d[5]=f2bf(f1.y); d[6]=f2bf(f1.z); d[7]=f2bf(f1.w);
        }
        __syncthreads();

        short8 af0 = *(const short8*)(As + (wave * 32 +  0 + lm) * LDA + lq * 8);
        short8 af1 = *(const short8*)(As + (wave * 32 + 16 + lm) * LDA + lq * 8);
        #pragma unroll
        for (int nt = 0; nt < 4; ++nt) {
            short8 bf = *(const short8*)(Ws + (nt * 16 + lm) * LDA + lq * 8);
            acc[0][nt] = __builtin_amdgcn_mfma_f32_16x16x32_bf16(af0, bf, acc[0][nt], 0, 0, 0);
            acc[1][nt] = __builtin_amdgcn_mfma_f32_16x16x32_bf16(af1, bf, acc[1][nt], 0, 0, 0);
        }
        __syncthreads();
    }

    #pragma unroll
    for (int nt = 0; nt < 4; ++nt) {
        const int n = nbase + nt * 16 + lm;
        const float bias = b1[n] + b2[n];
        #pragma unroll
        for (int mt = 0; mt < 2; ++mt) {
            const int mrow = mbase + wave * 32 + mt * 16 + lq * 4;
            #pragma unroll
            for (int r = 0; r < 4; ++r)
                out[(size_t)(mrow + r) * 512 + n] = f2h((acc[mt][nt][r] + bias) * oscale);
        }
    }
}

// ---------------------------------------------------------------------------
// rec13: 256 WGs x 512 thr (8 waves, 2/SIMD). WG pair (2b, 2b+1) both own
// real batch b (bb = bg>>1); all 16 lm rows replicate it; global stores
// masked to (bg even && lm==0). Per-CU work identical to R12 -- all 256 CUs
// busy (DVFS probe). Wave owns 4 j-tiles; W_hh(i8) slice in 128 AGPRs.
// h state: i8 LDS [2][16 b][512 j], 16B-granule swizzle g' = g ^ lm.
// j-pipelined: MFMA(j) ; epi(j-1). xv prefetched one full step ahead.
// xp is f16: consumed directly by v_fma_mix_f32 (no perm extraction).
// MODE 0: store h_t bf16 to hs_out (in-place over xp). MODE 1: t=511 -> h_last.
// ---------------------------------------------------------------------------

#define MFMA_J(JJ, BFR)                                                        \
  {                                                                            \
    acc[JJ] = __builtin_amdgcn_mfma_i32_16x16x64_i8(wa[JJ][0], BFR[0], z4, 0, 0, 0); \
    _Pragma("unroll")                                                          \
    for (int kt = 1; kt < 8; ++kt)                                             \
      acc[JJ] = __builtin_amdgcn_mfma_i32_16x16x64_i8(wa[JJ][kt], BFR[kt], acc[JJ], 0, 0, 0); \
  }

#define EPI_J(JJ, XVROW, HWBUF, TCUR)                                          \
  {                                                                            \
    const int jtg = wave * 4 + (JJ);                                           \
    float a0 = (float)acc[JJ][0], a1 = (float)acc[JJ][1];                       \
    float a2 = (float)acc[JJ][2], a3 = (float)acc[JJ][3];                       \
    float z0, z1, z2, z3;                                                       \
    asm("v_fma_mix_f32 %0, %1, %2, %3 op_sel:[0,0,0] op_sel_hi:[0,0,1]"         \
        : "=v"(z0) : "v"(a0), "v"(sc[JJ][0]), "v"(XVROW[JJ].x));                \
    asm("v_fma_mix_f32 %0, %1, %2, %3 op_sel:[0,0,1] op_sel_hi:[0,0,1]"         \
        : "=v"(z1) : "v"(a1), "v"(sc[JJ][1]), "v"(XVROW[JJ].x));                \
    asm("v_fma_mix_f32 %0, %1, %2, %3 op_sel:[0,0,0] op_sel_hi:[0,0,1]"         \
        : "=v"(z2) : "v"(a2), "v"(sc[JJ][2]), "v"(XVROW[JJ].y));                \
    asm("v_fma_mix_f32 %0, %1, %2, %3 op_sel:[0,0,1] op_sel_hi:[0,0,1]"         \
        : "=v"(z3) : "v"(a3), "v"(sc[JJ][3]), "v"(XVROW[JJ].y));                \
    float e0 = __builtin_amdgcn_exp2f(z0);                                      \
    float e1 = __builtin_amdgcn_exp2f(z1);                                      \
    float e2 = __builtin_amdgcn_exp2f(z2);                                      \
    float e3 = __builtin_amdgcn_exp2f(z3);                                      \
    float q0 = fmaf(-2.f, __builtin_amdgcn_rcpf(e0 + 1.f), 1.f);                \
    float q1 = fmaf(-2.f, __builtin_amdgcn_rcpf(e1 + 1.f), 1.f);                \
    float q2 = fmaf(-2.f, __builtin_amdgcn_rcpf(e2 + 1.f), 1.f);                \
    float q3 = fmaf(-2.f, __builtin_amdgcn_rcpf(e3 + 1.f), 1.f);                \
    unsigned m0 = __float_as_uint(fmaf(q0, 127.f, 12582912.f));                 \
    unsigned m1 = __float_as_uint(fmaf(q1, 127.f, 12582912.f));                 \
    unsigned m2 = __float_as_uint(fmaf(q2, 127.f, 12582912.f));                 \
    unsigned m3 = __float_as_uint(fmaf(q3, 127.f, 12582912.f));                 \
    unsigned lo = __builtin_amdgcn_perm(m1, m0, 0x00000400u);                   \
    unsigned hi = __builtin_amdgcn_perm(m3, m2, 0x00000400u);                   \
    unsigned qb = __builtin_amdgcn_perm(hi, lo, 0x05040100u);                   \
    *(unsigned*)((HWBUF) + lm * 512 + ((jtg ^ lm) << 4) + lq * 4) = qb;         \
    if (MODE == 0) {                                                            \
      if (st_en) {                                                              \
        uint2 st;                                                               \
        st.x = __builtin_amdgcn_perm(__float_as_uint(q1), __float_as_uint(q0), 0x07060302u); \
        st.y = __builtin_amdgcn_perm(__float_as_uint(q3), __float_as_uint(q2), 0x07060302u); \
        *(uint2*)(hst + (JJ) * 16) = st;                                        \
      }                                                                         \
    } else if ((TCUR) == 511) {                                                 \
      if (st_en) {                                                              \
        float4 o; o.x = q0; o.y = q1; o.z = q2; o.w = q3;                       \
        *(float4*)(h_last + (size_t)bb * 512 + jtg * 16 + lq * 4) = o;          \
      }                                                                         \
    }                                                                           \
  }

#define REC_STEP(P, TCUR)                                                      \
  {                                                                            \
    i32x4 bfr[8];                                                              \
    _Pragma("unroll")                                                          \
    for (int kt = 0; kt < 8; ++kt)                                             \
      bfr[kt] = *(const i32x4*)(&h2[P][0] + lm * 512 + ((((kt << 2) + lq)) ^ lm) * 16); \
    if ((TCUR) < 511) {                                                        \
      _Pragma("unroll")                                                        \
      for (int j = 0; j < 4; ++j)                                              \
        xv[(P) ^ 1][j] = *(const uint2*)(xpt + j * 16);                        \
      xpt += 65536;                                                            \
    }                                                                          \
    MFMA_J(0, bfr);                                                            \
    _Pragma("unroll")                                                          \
    for (int j = 1; j < 4; ++j) {                                              \
      MFMA_J(j, bfr);                                                          \
      EPI_J(j - 1, xv[P], &h2[(P) ^ 1][0], TCUR);                              \
    }                                                                          \
    EPI_J(3, xv[P], &h2[(P) ^ 1][0], TCUR);                                    \
    if (MODE == 0) hst += 65536;                                               \
    lds_barrier();                                                             \
  }

template <int MODE>
__global__ __launch_bounds__(512, 2) void rec13_kernel(
    const signed char* __restrict__ Wq,   // [32 jtg][8 kt][64 lane][16] i8
    const float* __restrict__ sc2,        // [512] row scale * 2log2e / 127^2
    const unsigned short* xp,             // [S][B][H] f16 SCALED (aliases hs_out)
    unsigned short* hs_out,               // [S][B][H] bf16
    float* __restrict__ h_last)           // [B][H] fp32
{
    __shared__ unsigned char h2[2][16 * 512];   // 16 KB

    const int tid  = threadIdx.x;
    const int lane = tid & 63;
    const int wave = tid >> 6;              // 0..7
    const int lm   = lane & 15, lq = lane >> 4;
    const int bg   = blockIdx.x;            // 0..255
    const int bb   = bg >> 1;               // real batch; 2 WGs per batch
    const bool st_en = ((bg & 1) == 0) && (lm == 0);

    // ---- W slice in AGPRs: 4 jtg x 8 kt x int4 = 128 AGPRs per wave ----
    i32x4 wa[4][8];
    #pragma unroll
    for (int j = 0; j < 4; ++j) {
        const int jtg = wave * 4 + j;
        #pragma unroll
        for (int kt = 0; kt < 8; ++kt)
            wa[j][kt] = *(const i32x4*)(Wq + ((size_t)((jtg * 8 + kt) * 64 + lane)) * 16);
    }
    #pragma unroll
    for (int j = 0; j < 4; ++j)
        #pragma unroll
        for (int kt = 0; kt < 8; ++kt)
            PINA(wa[j][kt]);

    // ---- per-lane fused dequant scales, pinned ----
    f32x4 sc[4];
    #pragma unroll
    for (int j = 0; j < 4; ++j)
        sc[j] = *(const f32x4*)(sc2 + (wave * 4 + j) * 16 + lq * 4);
    #pragma unroll
    for (int j = 0; j < 4; ++j) PINV(sc[j]);

    // ---- zero h buffers ----
    for (int i = tid; i < 4096; i += 512) ((int*)h2)[i] = 0;
    __syncthreads();

    // per-thread streaming pointers (row stride 128*512 elems per step)
    const unsigned short* xpt = xp + (size_t)bb * 512 + wave * 64 + lq * 4;
    unsigned short*       hst = hs_out + (size_t)bb * 512 + wave * 64 + lq * 4;

    uint2 xv[2][4];
    i32x4 acc[4];
    const i32x4 z4 = {0, 0, 0, 0};

    // ---- prologue: xv[0] = row 0 ----
    #pragma unroll
    for (int j = 0; j < 4; ++j) xv[0][j] = *(const uint2*)(xpt + j * 16);
    xpt += 65536;

    for (int t = 0; t < 512; t += 2) {
        REC_STEP(0, t);
        REC_STEP(1, t + 1);
    }
}

// ---------------------------------------------------------------------------
// head: logits[b][c] = h_last[b][:]·W_out[c][:] + b_out[c]; log_softmax rows.
// ---------------------------------------------------------------------------
__global__ __launch_bounds__(256, 2) void head_kernel(
    const float* __restrict__ hl, const float* __restrict__ Wout,
    const float* __restrict__ bout, float* __restrict__ out)
{
    __shared__ float hrow[512];
    __shared__ float lg[1000];
    __shared__ float red[8];
    const int b = blockIdx.x, tid = threadIdx.x;

    hrow[tid]       = hl[(size_t)b * 512 + tid];
    hrow[tid + 256] = hl[(size_t)b * 512 + 256 + tid];
    __syncthreads();

    float lmax = -1e30f;
    for (int c = tid; c < 1000; c += 256) {
        const float4* w4 = (const float4*)(Wout + (size_t)c * 512);
        float a0 = 0.f, a1 = 0.f, a2 = 0.f, a3 = 0.f;
        #pragma unroll 4
        for (int k = 0; k < 128; ++k) {
            float4 w = w4[k];
            a0 += hrow[4 * k + 0] * w.x;
            a1 += hrow[4 * k + 1] * w.y;
            a2 += hrow[4 * k + 2] * w.z;
            a3 += hrow[4 * k + 3] * w.w;
        }
        float acc = bout[c] + (a0 + a1) + (a2 + a3);
        lg[c] = acc;
        lmax = fmaxf(lmax, acc);
    }
    #pragma unroll
    for (int off = 32; off; off >>= 1) lmax = fmaxf(lmax, __shfl_down(lmax, off, 64));
    if ((tid & 63) == 0) red[tid >> 6] = lmax;
    __syncthreads();
    if (tid == 0) red[4] = fmaxf(fmaxf(red[0], red[1]), fmaxf(red[2], red[3]));
    __syncthreads();
    const float M = red[4];

    float lsum = 0.f;
    for (int c = tid; c < 1000; c += 256) lsum += __expf(lg[c] - M);
    #pragma unroll
    for (int off = 32; off; off >>= 1) lsum += __shfl_down(lsum, off, 64);
    __syncthreads();
    if ((tid & 63) == 0) red[tid >> 6] = lsum;
    __syncthreads();
    if (tid == 0) red[5] = M + __logf(red[0] + red[1] + red[2] + red[3]);
    __syncthreads();
    const float lse = red[5];

    for (int c = tid; c < 1000; c += 256)
        out[(size_t)b * 1000 + c] = lg[c] - lse;
}

// ---------------------------------------------------------------------------
extern "C" void kernel_launch(void* const* d_in, const int* in_sizes, int n_in,
                              void* d_out, int out_size, void* d_ws, size_t ws_size,
                              hipStream_t stream)
{
    const float* x    = (const float*)d_in[0];
    const float* Wih0 = (const float*)d_in[1];
    const float* Whh0 = (const float*)d_in[2];
    const float* bih0 = (const float*)d_in[3];
    const float* bhh0 = (const float*)d_in[4];
    const float* Wih1 = (const float*)d_in[5];
    const float* Whh1 = (const float*)d_in[6];
    const float* bih1 = (const float*)d_in[7];
    const float* bhh1 = (const float*)d_in[8];
    const float* Wout = (const float*)d_in[9];
    const float* bout = (const float*)d_in[10];
    float* out = (float*)d_out;

    char* ws = (char*)d_ws;
    unsigned short* bufA = (unsigned short*)ws;                              // 64 MB
    unsigned short* bufB = (unsigned short*)(ws + (size_t)64 * 1024 * 1024);
    signed char* Wq0 = (signed char*)bufB;                                   // 256 KB (dead after rec0)
    float*       sc0 = (float*)((char*)bufB + 262144);                       // 2 KB
    signed char* Wq1 = (signed char*)bufA;                                   // 256 KB (after proj1 consumed bufA)
    float*       sc1 = (float*)(ws + 262144);                                // 2 KB
    float*     hlast = (float*)(ws + (size_t)1 * 1024 * 1024);               // 256 KB

    const dim3 pgrid(8, 512);

    packi8_kernel<<<512, 64, 0, stream>>>(Whh0, Wq0, sc0);
    proj_kernel<128, 0><<<pgrid, 256, 0, stream>>>((const void*)x, Wih0, bih0, bhh0, bufA, TWO_LOG2E);
    rec13_kernel<0><<<256, 512, 0, stream>>>(Wq0, sc0, bufA, bufA, hlast);

    proj_kernel<512, 1><<<pgrid, 256, 0, stream>>>((const void*)bufA, Wih1, bih1, bhh1, bufB, TWO_LOG2E);
    packi8_kernel<<<512, 64, 0, stream>>>(Whh1, Wq1, sc1);
    rec13_kernel<1><<<256, 512, 0, stream>>>(Wq1, sc1, bufB, bufB, hlast);

    head_kernel<<<128, 256, 0, stream>>>(hlast, Wout, bout, out);
}

// Round 4
// 1453.652 us; speedup vs baseline: 1.3751x; 1.0405x over previous
//
#include <hip/hip_runtime.h>

// ============================================================================
// 2-layer tanh RNN (B=128,S=512,IN=128,H=512) + linear head (C=1000) + logsoftmax
//
// Round-14: force phase overlap with sched_group_barrier (T19).
//   Evidence through R13: DVFS dead (8/64/256 CU -> same 715 us), fma_mix
//   null -> VALU not binding. Step 3353 cy ~= serial sum of [LDS burst ~850
//   CU-wide] + [MFMA 1306/SIMD] + [EPI VALU+trans ~830/SIMD]; fully
//   overlapped floor ~1900. The per-step barrier phase-locks waves, so TLP
//   never covers the phases; the scheduler doesn't keep the source
//   interleave. Fix: pin it at compile time.
//   - chain j0: ds_reads paced 3-ahead into the dependent MFMA chain
//     (SGB pattern {VMEM 4}{DS_READ 3} 5x{MFMA 1,DS_READ 1}{MFMA 3}).
//   - chains j1..j3: 8x{MFMA 1, VALU 4} so EPI(j-1) trans/VALU fills the
//     ~20-cy gaps between dependent MFMAs.
//   - EPI split into branchless EPI_MAIN (+ds_write) and divergent EPI_ST so
//     each region stays one scheduling BB; xv prefetch made branchless
//     (always load, select-advance; in-bounds dummy reload at t=511).
//   - 64 WGs (R12 mapping: bb=bg*2+(lm&1), stores lm<2) - lowest HBM.
//   Numerics bit-identical to R13.
//
// ws layout: bufA = ws (64 MB): xp0/hs0 in place; later Wq1 head + hlast @
//            +1MB. bufB = ws+64MB: Wq0/sc0 head (dead after rec0), later xp1.
// ============================================================================

using short8  = __attribute__((ext_vector_type(8))) short;
using floatx4 = __attribute__((ext_vector_type(4))) float;
using i32x4   = __attribute__((ext_vector_type(4))) int;
using f32x4   = __attribute__((ext_vector_type(4))) float;

#define DEV static __device__ __forceinline__
#define PINA(x) asm volatile("" : "+a"(x))
#define PINV(x) asm volatile("" : "+v"(x))

#define TWO_LOG2E 2.8853900817779268f

#define SGB(m, n) __builtin_amdgcn_sched_group_barrier((m), (n), 0)

DEV void lds_barrier() {
    // LDS-only barrier: do NOT drain vmcnt (global stores/loads keep flying).
    asm volatile("s_waitcnt lgkmcnt(0)\n\ts_barrier" ::: "memory");
}

DEV unsigned short f2bf(float f) {
    union { float f; unsigned u; } v; v.f = f;
    unsigned r = (v.u + 0x7fffu + ((v.u >> 16) & 1u)) >> 16;
    return (unsigned short)r;
}

DEV unsigned short f2h(float f) {
    union { _Float16 h; unsigned short u; } c; c.h = (_Float16)f;
    return c.u;
}

// ---------------------------------------------------------------------------
// packi8: one block (64 thr) per W row j. Row absmax -> per-row scale;
// quantize to i8 in A-frag layout for mfma_i32_16x16x64_i8.
// sc2[j] = mx_j / 127^2 * 2*log2(e)  (dequant folded into exp2 argument).
// ---------------------------------------------------------------------------
__global__ __launch_bounds__(64) void packi8_kernel(
    const float* __restrict__ W, signed char* __restrict__ Wq,
    float* __restrict__ sc2)
{
    const int j = blockIdx.x;            // 0..511
    const int t = threadIdx.x;           // 0..63
    const float* row = W + (size_t)j * 512;

    float4 a = *(const float4*)(row + t * 8);
    float4 b = *(const float4*)(row + t * 8 + 4);
    float m = fmaxf(fmaxf(fabsf(a.x), fabsf(a.y)), fmaxf(fabsf(a.z), fabsf(a.w)));
    m = fmaxf(m, fmaxf(fmaxf(fabsf(b.x), fabsf(b.y)), fmaxf(fabsf(b.z), fabsf(b.w))));
    #pragma unroll
    for (int off = 32; off; off >>= 1) m = fmaxf(m, __shfl_down(m, off, 64));
    m = __shfl(m, 0, 64);
    if (t == 0) sc2[j] = m * (1.0f / (127.f * 127.f)) * TWO_LOG2E;

    if (t < 32) {
        const int kt = t >> 2, lq = t & 3;
        const int jtg = j >> 4, lm = j & 15;
        const float r = 127.f / m;
        int w4[4];
        #pragma unroll
        for (int w = 0; w < 4; ++w) {
            int v = 0;
            #pragma unroll
            for (int e = 0; e < 4; ++e) {
                int q = __float2int_rn(row[kt * 64 + lq * 16 + w * 4 + e] * r);
                v |= (q & 255) << (8 * e);
            }
            w4[w] = v;
        }
        i32x4 pk; pk[0] = w4[0]; pk[1] = w4[1]; pk[2] = w4[2]; pk[3] = w4[3];
        *(i32x4*)(Wq + ((size_t)((jtg * 8 + kt) * 64 + lq * 16 + lm)) * 16) = pk;
    }
}

// ---------------------------------------------------------------------------
// proj: out[m=t*128+b][n] = f16( (A[m][:]·W[n][:] + b1[n]+b2[n]) * oscale )
// oscale = 2*log2(e): rec consumes xp only inside exp2 arguments (via
// v_fma_mix_f32, so xp lives as packed f16).
// ---------------------------------------------------------------------------
template <int K, int MODE>
__global__ __launch_bounds__(256, 2) void proj_kernel(
    const void* __restrict__ Aptr, const float* __restrict__ W,
    const float* __restrict__ b1, const float* __restrict__ b2,
    unsigned short* __restrict__ out, float oscale)
{
    constexpr int LDA = 40;
    __shared__ unsigned short As[128 * LDA];
    __shared__ unsigned short Ws[64 * LDA];

    const int tid  = threadIdx.x;
    const int lane = tid & 63, wave = tid >> 6;
    const int lm   = lane & 15, lq = lane >> 4;
    const int nbase = blockIdx.x * 64;
    const int mtile = blockIdx.y;
    const int mbase = mtile * 128;

    floatx4 acc[2][4] = {};

    const int ar = tid >> 1, ak = (tid & 1) * 16;
    const int wr = tid >> 2, wk = (tid & 3) * 8;

    for (int k0 = 0; k0 < K; k0 += 32) {
        if (MODE == 0) {
            const float* x   = (const float*)Aptr;
            const float* src = x + ((size_t)ar * 512 + mtile) * 128 + (k0 + ak);
            float4 f0 = *(const float4*)(src + 0);
            float4 f1 = *(const float4*)(src + 4);
            float4 f2 = *(const float4*)(src + 8);
            float4 f3 = *(const float4*)(src + 12);
            unsigned short* d = As + ar * LDA + ak;
            d[0]=f2bf(f0.x); d[1]=f2bf(f0.y); d[2]=f2bf(f0.z); d[3]=f2bf(f0.w);
            d[4]=f2bf(f1.x); d[5]=f2bf(f1.y); d[6]=f2bf(f1.z); d[7]=f2bf(f1.w);
            d[8]=f2bf(f2.x); d[9]=f2bf(f2.y); d[10]=f2bf(f2.z); d[11]=f2bf(f2.w);
            d[12]=f2bf(f3.x); d[13]=f2bf(f3.y); d[14]=f2bf(f3.z); d[15]=f2bf(f3.w);
        } else {
            const unsigned short* h =
                (const unsigned short*)Aptr + (size_t)(mbase + ar) * K + k0 + ak;
            short8 v0 = *(const short8*)(h);
            short8 v1 = *(const short8*)(h + 8);
            *(short8*)(As + ar * LDA + ak)     = v0;
            *(short8*)(As + ar * LDA + ak + 8) = v1;
        }
        {
            const float* src = W + (size_t)(nbase + wr) * K + k0 + wk;
            float4 f0 = *(const float4*)(src);
            float4 f1 = *(const float4*)(src + 4);
            unsigned short* d = Ws + wr * LDA + wk;
            d[0]=f2bf(f0.x); d[1]=f2bf(f0.y); d[2]=f2bf(f0.z); d[3]=f2bf(f0.w);
            d[4]=f2bf(f1.x); d[5]=f2bf(f1.y); d[6]=f2bf(f1.z); d[7]=f2bf(f1.w);
        }
        __syncthreads();

        short8 af0 = *(const short8*)(As + (wave * 32 +  0 + lm) * LDA + lq * 8);
        short8 af1 = *(const short8*)(As + (wave * 32 + 16 + lm) * LDA + lq * 8);
        #pragma unroll
        for (int nt = 0; nt < 4; ++nt) {
            short8 bf = *(const short8*)(Ws + (nt * 16 + lm) * LDA + lq * 8);
            acc[0][nt] = __builtin_amdgcn_mfma_f32_16x16x32_bf16(af0, bf, acc[0][nt], 0, 0, 0);
            acc[1][nt] = __builtin_amdgcn_mfma_f32_16x16x32_bf16(af1, bf, acc[1][nt], 0, 0, 0);
        }
        __syncthreads();
    }

    #pragma unroll
    for (int nt = 0; nt < 4; ++nt) {
        const int n = nbase + nt * 16 + lm;
        const float bias = b1[n] + b2[n];
        #pragma unroll
        for (int mt = 0; mt < 2; ++mt) {
            const int mrow = mbase + wave * 32 + mt * 16 + lq * 4;
            #pragma unroll
            for (int r = 0; r < 4; ++r)
                out[(size_t)(mrow + r) * 512 + n] = f2h((acc[mt][nt][r] + bias) * oscale);
        }
    }
}

// ---------------------------------------------------------------------------
// rec14: 64 WGs x 512 thr (8 waves, 2/SIMD). WG bg owns real batches
// {2bg, 2bg+1} (bb = bg*2 + (lm&1)); lanes lm>=2 replicate; stores lm<2.
// Wave owns 4 j-tiles; W_hh(i8) slice in 128 AGPRs per wave.
// h state: i8 LDS [2][16 b][512 j], 16B-granule swizzle g' = g ^ lm.
// sched_group_barrier pins reads-into-chain0 and EPI-into-chain interleave.
// MODE 0: store h_t bf16 to hs_out (in-place over xp). MODE 1: t=511 -> h_last.
// ---------------------------------------------------------------------------

#define RD8(P, KT)                                                             \
  (*(const i32x4*)(&h2[P][0] + lm * 512 + ((((KT) * 4 + lq) ^ lm) << 4)))

#define MFMA_ONE(JJ, KT)                                                       \
  acc[JJ] = __builtin_amdgcn_mfma_i32_16x16x64_i8(                             \
      wa[JJ][KT], bfr[KT], (KT) == 0 ? z4 : acc[JJ], 0, 0, 0)

#define MFMA_J(JJ, BFR)                                                        \
  {                                                                            \
    acc[JJ] = __builtin_amdgcn_mfma_i32_16x16x64_i8(wa[JJ][0], BFR[0], z4, 0, 0, 0); \
    _Pragma("unroll")                                                          \
    for (int kt = 1; kt < 8; ++kt)                                             \
      acc[JJ] = __builtin_amdgcn_mfma_i32_16x16x64_i8(wa[JJ][kt], BFR[kt], acc[JJ], 0, 0, 0); \
  }

// branchless part of the epilogue (stays in the same scheduling region)
#define EPI_MAIN(JJ, XVROW, HWBUF, QV)                                         \
  {                                                                            \
    const int jtg = wave * 4 + (JJ);                                           \
    float a0 = (float)acc[JJ][0], a1 = (float)acc[JJ][1];                      \
    float a2 = (float)acc[JJ][2], a3 = (float)acc[JJ][3];                      \
    float z0, z1, z2, z3;                                                      \
    asm("v_fma_mix_f32 %0, %1, %2, %3 op_sel:[0,0,0] op_sel_hi:[0,0,1]"        \
        : "=v"(z0) : "v"(a0), "v"(sc[JJ][0]), "v"(XVROW[JJ].x));               \
    asm("v_fma_mix_f32 %0, %1, %2, %3 op_sel:[0,0,1] op_sel_hi:[0,0,1]"        \
        : "=v"(z1) : "v"(a1), "v"(sc[JJ][1]), "v"(XVROW[JJ].x));               \
    asm("v_fma_mix_f32 %0, %1, %2, %3 op_sel:[0,0,0] op_sel_hi:[0,0,1]"        \
        : "=v"(z2) : "v"(a2), "v"(sc[JJ][2]), "v"(XVROW[JJ].y));               \
    asm("v_fma_mix_f32 %0, %1, %2, %3 op_sel:[0,0,1] op_sel_hi:[0,0,1]"        \
        : "=v"(z3) : "v"(a3), "v"(sc[JJ][3]), "v"(XVROW[JJ].y));               \
    float e0 = __builtin_amdgcn_exp2f(z0);                                     \
    float e1 = __builtin_amdgcn_exp2f(z1);                                     \
    float e2 = __builtin_amdgcn_exp2f(z2);                                     \
    float e3 = __builtin_amdgcn_exp2f(z3);                                     \
    float q0 = fmaf(-2.f, __builtin_amdgcn_rcpf(e0 + 1.f), 1.f);               \
    float q1 = fmaf(-2.f, __builtin_amdgcn_rcpf(e1 + 1.f), 1.f);               \
    float q2 = fmaf(-2.f, __builtin_amdgcn_rcpf(e2 + 1.f), 1.f);               \
    float q3 = fmaf(-2.f, __builtin_amdgcn_rcpf(e3 + 1.f), 1.f);               \
    QV.x = q0; QV.y = q1; QV.z = q2; QV.w = q3;                                \
    unsigned m0 = __float_as_uint(fmaf(q0, 127.f, 12582912.f));                \
    unsigned m1 = __float_as_uint(fmaf(q1, 127.f, 12582912.f));                \
    unsigned m2 = __float_as_uint(fmaf(q2, 127.f, 12582912.f));                \
    unsigned m3 = __float_as_uint(fmaf(q3, 127.f, 12582912.f));                \
    unsigned lo = __builtin_amdgcn_perm(m1, m0, 0x00000400u);                  \
    unsigned hi = __builtin_amdgcn_perm(m3, m2, 0x00000400u);                  \
    unsigned qb = __builtin_amdgcn_perm(hi, lo, 0x05040100u);                  \
    *(unsigned*)((HWBUF) + lm * 512 + ((jtg ^ lm) << 4) + lq * 4) = qb;        \
  }

// divergent global-store part (opens a new basic block; kept out of SGB regions)
#define EPI_ST(JJ, QV, TCUR)                                                   \
  {                                                                            \
    if (MODE == 0) {                                                           \
      if (lm < 2) {                                                            \
        uint2 st;                                                              \
        st.x = __builtin_amdgcn_perm(__float_as_uint(QV.y), __float_as_uint(QV.x), 0x07060302u); \
        st.y = __builtin_amdgcn_perm(__float_as_uint(QV.w), __float_as_uint(QV.z), 0x07060302u); \
        *(uint2*)(hst + (JJ) * 16) = st;                                       \
      }                                                                        \
    } else if ((TCUR) == 511) {                                                \
      if (lm < 2) {                                                            \
        const int jtg = wave * 4 + (JJ);                                       \
        *(float4*)(h_last + (size_t)bb * 512 + jtg * 16 + lq * 4) = QV;        \
      }                                                                        \
    }                                                                          \
  }

#define SGB8_MIX()                                                             \
  {                                                                            \
    _Pragma("unroll")                                                          \
    for (int u = 0; u < 8; ++u) { SGB(0x8, 1); SGB(0x2, 4); }                  \
  }

#define REC_STEP(P, TCUR)                                                      \
  {                                                                            \
    i32x4 bfr[8];                                                              \
    float4 qv0, qv1, qv2, qv3;                                                 \
    _Pragma("unroll")                                                          \
    for (int j = 0; j < 4; ++j)                                                \
      xv[(P) ^ 1][j] = *(const uint2*)(xpt + j * 16);                          \
    xpt += ((TCUR) < 510) ? 65536 : 0;                                         \
    bfr[0] = RD8(P, 0);                                                        \
    bfr[1] = RD8(P, 1);                                                        \
    bfr[2] = RD8(P, 2);                                                        \
    MFMA_ONE(0, 0);                                                            \
    bfr[3] = RD8(P, 3);                                                        \
    MFMA_ONE(0, 1);                                                            \
    bfr[4] = RD8(P, 4);                                                        \
    MFMA_ONE(0, 2);                                                            \
    bfr[5] = RD8(P, 5);                                                        \
    MFMA_ONE(0, 3);                                                            \
    bfr[6] = RD8(P, 6);                                                        \
    MFMA_ONE(0, 4);                                                            \
    bfr[7] = RD8(P, 7);                                                        \
    MFMA_ONE(0, 5);                                                            \
    MFMA_ONE(0, 6);                                                            \
    MFMA_ONE(0, 7);                                                            \
    SGB(0x20, 4);   /* xv loads issue first */                                 \
    SGB(0x100, 3);  /* 3 ds_reads ahead */                                     \
    SGB(0x8, 1); SGB(0x100, 1);                                                \
    SGB(0x8, 1); SGB(0x100, 1);                                                \
    SGB(0x8, 1); SGB(0x100, 1);                                                \
    SGB(0x8, 1); SGB(0x100, 1);                                                \
    SGB(0x8, 1); SGB(0x100, 1);                                                \
    SGB(0x8, 3);                                                               \
    MFMA_J(1, bfr);                                                            \
    EPI_MAIN(0, xv[P], &h2[(P) ^ 1][0], qv0);                                  \
    SGB8_MIX();                                                                \
    EPI_ST(0, qv0, TCUR);                                                      \
    MFMA_J(2, bfr);                                                            \
    EPI_MAIN(1, xv[P], &h2[(P) ^ 1][0], qv1);                                  \
    SGB8_MIX();                                                                \
    EPI_ST(1, qv1, TCUR);                                                      \
    MFMA_J(3, bfr);                                                            \
    EPI_MAIN(2, xv[P], &h2[(P) ^ 1][0], qv2);                                  \
    SGB8_MIX();                                                                \
    EPI_ST(2, qv2, TCUR);                                                      \
    EPI_MAIN(3, xv[P], &h2[(P) ^ 1][0], qv3);                                  \
    EPI_ST(3, qv3, TCUR);                                                      \
    if (MODE == 0) hst += 65536;                                               \
    lds_barrier();                                                             \
  }

template <int MODE>
__global__ __launch_bounds__(512, 2) void rec14_kernel(
    const signed char* __restrict__ Wq,   // [32 jtg][8 kt][64 lane][16] i8
    const float* __restrict__ sc2,        // [512] row scale * 2log2e / 127^2
    const unsigned short* xp,             // [S][B][H] f16 SCALED (aliases hs_out)
    unsigned short* hs_out,               // [S][B][H] bf16
    float* __restrict__ h_last)           // [B][H] fp32
{
    __shared__ unsigned char h2[2][16 * 512];   // 16 KB

    const int tid  = threadIdx.x;
    const int lane = tid & 63;
    const int wave = tid >> 6;              // 0..7
    const int lm   = lane & 15, lq = lane >> 4;
    const int bg   = blockIdx.x;            // 0..63
    const int bb   = bg * 2 + (lm & 1);     // 2 real batches replicated over 16 rows

    // ---- W slice in AGPRs: 4 jtg x 8 kt x int4 = 128 AGPRs per wave ----
    i32x4 wa[4][8];
    #pragma unroll
    for (int j = 0; j < 4; ++j) {
        const int jtg = wave * 4 + j;
        #pragma unroll
        for (int kt = 0; kt < 8; ++kt)
            wa[j][kt] = *(const i32x4*)(Wq + ((size_t)((jtg * 8 + kt) * 64 + lane)) * 16);
    }
    #pragma unroll
    for (int j = 0; j < 4; ++j)
        #pragma unroll
        for (int kt = 0; kt < 8; ++kt)
            PINA(wa[j][kt]);

    // ---- per-lane fused dequant scales, pinned ----
    f32x4 sc[4];
    #pragma unroll
    for (int j = 0; j < 4; ++j)
        sc[j] = *(const f32x4*)(sc2 + (wave * 4 + j) * 16 + lq * 4);
    #pragma unroll
    for (int j = 0; j < 4; ++j) PINV(sc[j]);

    // ---- zero h buffers ----
    for (int i = tid; i < 4096; i += 512) ((int*)h2)[i] = 0;
    __syncthreads();

    // per-thread streaming pointers (row stride 128*512 elems per step)
    const unsigned short* xpt = xp + (size_t)bb * 512 + wave * 64 + lq * 4;
    unsigned short*       hst = hs_out + (size_t)bb * 512 + wave * 64 + lq * 4;

    uint2 xv[2][4];
    i32x4 acc[4];
    const i32x4 z4 = {0, 0, 0, 0};

    // ---- prologue: xv[0] = row 0 ----
    #pragma unroll
    for (int j = 0; j < 4; ++j) xv[0][j] = *(const uint2*)(xpt + j * 16);
    xpt += 65536;

    for (int t = 0; t < 512; t += 2) {
        REC_STEP(0, t);
        REC_STEP(1, t + 1);
    }
}

// ---------------------------------------------------------------------------
// head: logits[b][c] = h_last[b][:]·W_out[c][:] + b_out[c]; log_softmax rows.
// ---------------------------------------------------------------------------
__global__ __launch_bounds__(256, 2) void head_kernel(
    const float* __restrict__ hl, const float* __restrict__ Wout,
    const float* __restrict__ bout, float* __restrict__ out)
{
    __shared__ float hrow[512];
    __shared__ float lg[1000];
    __shared__ float red[8];
    const int b = blockIdx.x, tid = threadIdx.x;

    hrow[tid]       = hl[(size_t)b * 512 + tid];
    hrow[tid + 256] = hl[(size_t)b * 512 + 256 + tid];
    __syncthreads();

    float lmax = -1e30f;
    for (int c = tid; c < 1000; c += 256) {
        const float4* w4 = (const float4*)(Wout + (size_t)c * 512);
        float a0 = 0.f, a1 = 0.f, a2 = 0.f, a3 = 0.f;
        #pragma unroll 4
        for (int k = 0; k < 128; ++k) {
            float4 w = w4[k];
            a0 += hrow[4 * k + 0] * w.x;
            a1 += hrow[4 * k + 1] * w.y;
            a2 += hrow[4 * k + 2] * w.z;
            a3 += hrow[4 * k + 3] * w.w;
        }
        float acc = bout[c] + (a0 + a1) + (a2 + a3);
        lg[c] = acc;
        lmax = fmaxf(lmax, acc);
    }
    #pragma unroll
    for (int off = 32; off; off >>= 1) lmax = fmaxf(lmax, __shfl_down(lmax, off, 64));
    if ((tid & 63) == 0) red[tid >> 6] = lmax;
    __syncthreads();
    if (tid == 0) red[4] = fmaxf(fmaxf(red[0], red[1]), fmaxf(red[2], red[3]));
    __syncthreads();
    const float M = red[4];

    float lsum = 0.f;
    for (int c = tid; c < 1000; c += 256) lsum += __expf(lg[c] - M);
    #pragma unroll
    for (int off = 32; off; off >>= 1) lsum += __shfl_down(lsum, off, 64);
    __syncthreads();
    if ((tid & 63) == 0) red[tid >> 6] = lsum;
    __syncthreads();
    if (tid == 0) red[5] = M + __logf(red[0] + red[1] + red[2] + red[3]);
    __syncthreads();
    const float lse = red[5];

    for (int c = tid; c < 1000; c += 256)
        out[(size_t)b * 1000 + c] = lg[c] - lse;
}

// ---------------------------------------------------------------------------
extern "C" void kernel_launch(void* const* d_in, const int* in_sizes, int n_in,
                              void* d_out, int out_size, void* d_ws, size_t ws_size,
                              hipStream_t stream)
{
    const float* x    = (const float*)d_in[0];
    const float* Wih0 = (const float*)d_in[1];
    const float* Whh0 = (const float*)d_in[2];
    const float* bih0 = (const float*)d_in[3];
    const float* bhh0 = (const float*)d_in[4];
    const float* Wih1 = (const float*)d_in[5];
    const float* Whh1 = (const float*)d_in[6];
    const float* bih1 = (const float*)d_in[7];
    const float* bhh1 = (const float*)d_in[8];
    const float* Wout = (const float*)d_in[9];
    const float* bout = (const float*)d_in[10];
    float* out = (float*)d_out;

    char* ws = (char*)d_ws;
    unsigned short* bufA = (unsigned short*)ws;                              // 64 MB
    unsigned short* bufB = (unsigned short*)(ws + (size_t)64 * 1024 * 1024);
    signed char* Wq0 = (signed char*)bufB;                                   // 256 KB (dead after rec0)
    float*       sc0 = (float*)((char*)bufB + 262144);                       // 2 KB
    signed char* Wq1 = (signed char*)bufA;                                   // 256 KB (after proj1 consumed bufA)
    float*       sc1 = (float*)(ws + 262144);                                // 2 KB
    float*     hlast = (float*)(ws + (size_t)1 * 1024 * 1024);               // 256 KB

    const dim3 pgrid(8, 512);

    packi8_kernel<<<512, 64, 0, stream>>>(Whh0, Wq0, sc0);
    proj_kernel<128, 0><<<pgrid, 256, 0, stream>>>((const void*)x, Wih0, bih0, bhh0, bufA, TWO_LOG2E);
    rec14_kernel<0><<<64, 512, 0, stream>>>(Wq0, sc0, bufA, bufA, hlast);

    proj_kernel<512, 1><<<pgrid, 256, 0, stream>>>((const void*)bufA, Wih1, bih1, bhh1, bufB, TWO_LOG2E);
    packi8_kernel<<<512, 64, 0, stream>>>(Whh1, Wq1, sc1);
    rec14_kernel<1><<<64, 512, 0, stream>>>(Wq1, sc1, bufB, bufB, hlast);

    head_kernel<<<128, 256, 0, stream>>>(hlast, Wout, bout, out);
}

// Round 5
// 1441.038 us; speedup vs baseline: 1.3872x; 1.0088x over previous
//
#include <hip/hip_runtime.h>

// ============================================================================
// 2-layer tanh RNN (B=128,S=512,IN=128,H=512) + linear head (C=1000) + logsoftmax
//
// Round-15: de-phase the SIMD wave pair (zero-cost chain rotation).
//   R14 (SGB interleave) got step 3353->2892 cy. Remaining ~1100 cy of
//   non-overlap: the per-step barrier phase-locks the 2 waves/SIMD and they
//   run IDENTICAL code, so both want MFMA issue in the chain regions and
//   VALU/trans in the EPI regions simultaneously; cross-wave MFMA|VALU
//   co-issue (m114) never happens. Fix: odd waves compute chains in order
//   [2,3,0,1] (even: [0,1,2,3]), EPIs follow their own chains. Chains are
//   independent (separate acc, disjoint ds_write granules, same kt order)
//   -> bit-identical numerics. Parity branch hoisted outside the t-loop.
//   Everything else identical to R14 (SGB pinning, f16 xp via fma_mix,
//   64 WGs, i8 AGPR-resident W_hh, swizzled i8 h LDS dbuf, lgkm-only barrier).
//
// ws layout: bufA = ws (64 MB): xp0/hs0 in place; later Wq1 head + hlast @
//            +1MB. bufB = ws+64MB: Wq0/sc0 head (dead after rec0), later xp1.
// ============================================================================

using short8  = __attribute__((ext_vector_type(8))) short;
using floatx4 = __attribute__((ext_vector_type(4))) float;
using i32x4   = __attribute__((ext_vector_type(4))) int;
using f32x4   = __attribute__((ext_vector_type(4))) float;

#define DEV static __device__ __forceinline__
#define PINA(x) asm volatile("" : "+a"(x))
#define PINV(x) asm volatile("" : "+v"(x))

#define TWO_LOG2E 2.8853900817779268f

#define SGB(m, n) __builtin_amdgcn_sched_group_barrier((m), (n), 0)

DEV void lds_barrier() {
    // LDS-only barrier: do NOT drain vmcnt (global stores/loads keep flying).
    asm volatile("s_waitcnt lgkmcnt(0)\n\ts_barrier" ::: "memory");
}

DEV unsigned short f2bf(float f) {
    union { float f; unsigned u; } v; v.f = f;
    unsigned r = (v.u + 0x7fffu + ((v.u >> 16) & 1u)) >> 16;
    return (unsigned short)r;
}

DEV unsigned short f2h(float f) {
    union { _Float16 h; unsigned short u; } c; c.h = (_Float16)f;
    return c.u;
}

// ---------------------------------------------------------------------------
// packi8: one block (64 thr) per W row j. Row absmax -> per-row scale;
// quantize to i8 in A-frag layout for mfma_i32_16x16x64_i8.
// sc2[j] = mx_j / 127^2 * 2*log2(e)  (dequant folded into exp2 argument).
// ---------------------------------------------------------------------------
__global__ __launch_bounds__(64) void packi8_kernel(
    const float* __restrict__ W, signed char* __restrict__ Wq,
    float* __restrict__ sc2)
{
    const int j = blockIdx.x;            // 0..511
    const int t = threadIdx.x;           // 0..63
    const float* row = W + (size_t)j * 512;

    float4 a = *(const float4*)(row + t * 8);
    float4 b = *(const float4*)(row + t * 8 + 4);
    float m = fmaxf(fmaxf(fabsf(a.x), fabsf(a.y)), fmaxf(fabsf(a.z), fabsf(a.w)));
    m = fmaxf(m, fmaxf(fmaxf(fabsf(b.x), fabsf(b.y)), fmaxf(fabsf(b.z), fabsf(b.w))));
    #pragma unroll
    for (int off = 32; off; off >>= 1) m = fmaxf(m, __shfl_down(m, off, 64));
    m = __shfl(m, 0, 64);
    if (t == 0) sc2[j] = m * (1.0f / (127.f * 127.f)) * TWO_LOG2E;

    if (t < 32) {
        const int kt = t >> 2, lq = t & 3;
        const int jtg = j >> 4, lm = j & 15;
        const float r = 127.f / m;
        int w4[4];
        #pragma unroll
        for (int w = 0; w < 4; ++w) {
            int v = 0;
            #pragma unroll
            for (int e = 0; e < 4; ++e) {
                int q = __float2int_rn(row[kt * 64 + lq * 16 + w * 4 + e] * r);
                v |= (q & 255) << (8 * e);
            }
            w4[w] = v;
        }
        i32x4 pk; pk[0] = w4[0]; pk[1] = w4[1]; pk[2] = w4[2]; pk[3] = w4[3];
        *(i32x4*)(Wq + ((size_t)((jtg * 8 + kt) * 64 + lq * 16 + lm)) * 16) = pk;
    }
}

// ---------------------------------------------------------------------------
// proj: out[m=t*128+b][n] = f16( (A[m][:]·W[n][:] + b1[n]+b2[n]) * oscale )
// oscale = 2*log2(e): rec consumes xp only inside exp2 arguments (via
// v_fma_mix_f32, so xp lives as packed f16).
// ---------------------------------------------------------------------------
template <int K, int MODE>
__global__ __launch_bounds__(256, 2) void proj_kernel(
    const void* __restrict__ Aptr, const float* __restrict__ W,
    const float* __restrict__ b1, const float* __restrict__ b2,
    unsigned short* __restrict__ out, float oscale)
{
    constexpr int LDA = 40;
    __shared__ unsigned short As[128 * LDA];
    __shared__ unsigned short Ws[64 * LDA];

    const int tid  = threadIdx.x;
    const int lane = tid & 63, wave = tid >> 6;
    const int lm   = lane & 15, lq = lane >> 4;
    const int nbase = blockIdx.x * 64;
    const int mtile = blockIdx.y;
    const int mbase = mtile * 128;

    floatx4 acc[2][4] = {};

    const int ar = tid >> 1, ak = (tid & 1) * 16;
    const int wr = tid >> 2, wk = (tid & 3) * 8;

    for (int k0 = 0; k0 < K; k0 += 32) {
        if (MODE == 0) {
            const float* x   = (const float*)Aptr;
            const float* src = x + ((size_t)ar * 512 + mtile) * 128 + (k0 + ak);
            float4 f0 = *(const float4*)(src + 0);
            float4 f1 = *(const float4*)(src + 4);
            float4 f2 = *(const float4*)(src + 8);
            float4 f3 = *(const float4*)(src + 12);
            unsigned short* d = As + ar * LDA + ak;
            d[0]=f2bf(f0.x); d[1]=f2bf(f0.y); d[2]=f2bf(f0.z); d[3]=f2bf(f0.w);
            d[4]=f2bf(f1.x); d[5]=f2bf(f1.y); d[6]=f2bf(f1.z); d[7]=f2bf(f1.w);
            d[8]=f2bf(f2.x); d[9]=f2bf(f2.y); d[10]=f2bf(f2.z); d[11]=f2bf(f2.w);
            d[12]=f2bf(f3.x); d[13]=f2bf(f3.y); d[14]=f2bf(f3.z); d[15]=f2bf(f3.w);
        } else {
            const unsigned short* h =
                (const unsigned short*)Aptr + (size_t)(mbase + ar) * K + k0 + ak;
            short8 v0 = *(const short8*)(h);
            short8 v1 = *(const short8*)(h + 8);
            *(short8*)(As + ar * LDA + ak)     = v0;
            *(short8*)(As + ar * LDA + ak + 8) = v1;
        }
        {
            const float* src = W + (size_t)(nbase + wr) * K + k0 + wk;
            float4 f0 = *(const float4*)(src);
            float4 f1 = *(const float4*)(src + 4);
            unsigned short* d = Ws + wr * LDA + wk;
            d[0]=f2bf(f0.x); d[1]=f2bf(f0.y); d[2]=f2bf(f0.z); d[3]=f2bf(f0.w);
            d[4]=f2bf(f1.x); d[5]=f2bf(f1.y); d[6]=f2bf(f1.z); d[7]=f2bf(f1.w);
        }
        __syncthreads();

        short8 af0 = *(const short8*)(As + (wave * 32 +  0 + lm) * LDA + lq * 8);
        short8 af1 = *(const short8*)(As + (wave * 32 + 16 + lm) * LDA + lq * 8);
        #pragma unroll
        for (int nt = 0; nt < 4; ++nt) {
            short8 bf = *(const short8*)(Ws + (nt * 16 + lm) * LDA + lq * 8);
            acc[0][nt] = __builtin_amdgcn_mfma_f32_16x16x32_bf16(af0, bf, acc[0][nt], 0, 0, 0);
            acc[1][nt] = __builtin_amdgcn_mfma_f32_16x16x32_bf16(af1, bf, acc[1][nt], 0, 0, 0);
        }
        __syncthreads();
    }

    #pragma unroll
    for (int nt = 0; nt < 4; ++nt) {
        const int n = nbase + nt * 16 + lm;
        const float bias = b1[n] + b2[n];
        #pragma unroll
        for (int mt = 0; mt < 2; ++mt) {
            const int mrow = mbase + wave * 32 + mt * 16 + lq * 4;
            #pragma unroll
            for (int r = 0; r < 4; ++r)
                out[(size_t)(mrow + r) * 512 + n] = f2h((acc[mt][nt][r] + bias) * oscale);
        }
    }
}

// ---------------------------------------------------------------------------
// rec15: 64 WGs x 512 thr (8 waves, 2/SIMD). WG bg owns real batches
// {2bg, 2bg+1} (bb = bg*2 + (lm&1)); lanes lm>=2 replicate; stores lm<2.
// Wave owns 4 j-tiles; W_hh(i8) slice in 128 AGPRs per wave.
// h state: i8 LDS [2][16 b][512 j], 16B-granule swizzle g' = g ^ lm.
// SGB pins reads-into-chain and EPI-into-chain interleave. Odd waves run the
// chain sequence rotated by 2 ([2,3,0,1]) so the SIMD's wave pair is phase-
// shifted: one wave's MFMA region overlaps the other's EPI region.
// MODE 0: store h_t bf16 to hs_out (in-place over xp). MODE 1: t=511 -> h_last.
// ---------------------------------------------------------------------------

#define RD8(P, KT)                                                             \
  (*(const i32x4*)(&h2[P][0] + lm * 512 + ((((KT) * 4 + lq) ^ lm) << 4)))

#define MFMA_ONE(JJ, KT)                                                       \
  acc[JJ] = __builtin_amdgcn_mfma_i32_16x16x64_i8(                             \
      wa[JJ][KT], bfr[KT], (KT) == 0 ? z4 : acc[JJ], 0, 0, 0)

#define MFMA_J(JJ, BFR)                                                        \
  {                                                                            \
    acc[JJ] = __builtin_amdgcn_mfma_i32_16x16x64_i8(wa[JJ][0], BFR[0], z4, 0, 0, 0); \
    _Pragma("unroll")                                                          \
    for (int kt = 1; kt < 8; ++kt)                                             \
      acc[JJ] = __builtin_amdgcn_mfma_i32_16x16x64_i8(wa[JJ][kt], BFR[kt], acc[JJ], 0, 0, 0); \
  }

// branchless part of the epilogue (stays in the same scheduling region)
#define EPI_MAIN(JJ, XVROW, HWBUF, QV)                                         \
  {                                                                            \
    const int jtg = wave * 4 + (JJ);                                           \
    float a0 = (float)acc[JJ][0], a1 = (float)acc[JJ][1];                      \
    float a2 = (float)acc[JJ][2], a3 = (float)acc[JJ][3];                      \
    float z0, z1, z2, z3;                                                      \
    asm("v_fma_mix_f32 %0, %1, %2, %3 op_sel:[0,0,0] op_sel_hi:[0,0,1]"        \
        : "=v"(z0) : "v"(a0), "v"(sc[JJ][0]), "v"(XVROW[JJ].x));               \
    asm("v_fma_mix_f32 %0, %1, %2, %3 op_sel:[0,0,1] op_sel_hi:[0,0,1]"        \
        : "=v"(z1) : "v"(a1), "v"(sc[JJ][1]), "v"(XVROW[JJ].x));               \
    asm("v_fma_mix_f32 %0, %1, %2, %3 op_sel:[0,0,0] op_sel_hi:[0,0,1]"        \
        : "=v"(z2) : "v"(a2), "v"(sc[JJ][2]), "v"(XVROW[JJ].y));               \
    asm("v_fma_mix_f32 %0, %1, %2, %3 op_sel:[0,0,1] op_sel_hi:[0,0,1]"        \
        : "=v"(z3) : "v"(a3), "v"(sc[JJ][3]), "v"(XVROW[JJ].y));               \
    float e0 = __builtin_amdgcn_exp2f(z0);                                     \
    float e1 = __builtin_amdgcn_exp2f(z1);                                     \
    float e2 = __builtin_amdgcn_exp2f(z2);                                     \
    float e3 = __builtin_amdgcn_exp2f(z3);                                     \
    float q0 = fmaf(-2.f, __builtin_amdgcn_rcpf(e0 + 1.f), 1.f);               \
    float q1 = fmaf(-2.f, __builtin_amdgcn_rcpf(e1 + 1.f), 1.f);               \
    float q2 = fmaf(-2.f, __builtin_amdgcn_rcpf(e2 + 1.f), 1.f);               \
    float q3 = fmaf(-2.f, __builtin_amdgcn_rcpf(e3 + 1.f), 1.f);               \
    QV.x = q0; QV.y = q1; QV.z = q2; QV.w = q3;                                \
    unsigned m0 = __float_as_uint(fmaf(q0, 127.f, 12582912.f));                \
    unsigned m1 = __float_as_uint(fmaf(q1, 127.f, 12582912.f));                \
    unsigned m2 = __float_as_uint(fmaf(q2, 127.f, 12582912.f));                \
    unsigned m3 = __float_as_uint(fmaf(q3, 127.f, 12582912.f));                \
    unsigned lo = __builtin_amdgcn_perm(m1, m0, 0x00000400u);                  \
    unsigned hi = __builtin_amdgcn_perm(m3, m2, 0x00000400u);                  \
    unsigned qb = __builtin_amdgcn_perm(hi, lo, 0x05040100u);                  \
    *(unsigned*)((HWBUF) + lm * 512 + ((jtg ^ lm) << 4) + lq * 4) = qb;        \
  }

// divergent global-store part (opens a new basic block; kept out of SGB regions)
#define EPI_ST(JJ, QV, TCUR)                                                   \
  {                                                                            \
    if (MODE == 0) {                                                           \
      if (lm < 2) {                                                            \
        uint2 st;                                                              \
        st.x = __builtin_amdgcn_perm(__float_as_uint(QV.y), __float_as_uint(QV.x), 0x07060302u); \
        st.y = __builtin_amdgcn_perm(__float_as_uint(QV.w), __float_as_uint(QV.z), 0x07060302u); \
        *(uint2*)(hst + (JJ) * 16) = st;                                       \
      }                                                                        \
    } else if ((TCUR) == 511) {                                                \
      if (lm < 2) {                                                            \
        const int jtg = wave * 4 + (JJ);                                       \
        *(float4*)(h_last + (size_t)bb * 512 + jtg * 16 + lq * 4) = QV;        \
      }                                                                        \
    }                                                                          \
  }

#define SGB8_MIX()                                                             \
  {                                                                            \
    _Pragma("unroll")                                                          \
    for (int u = 0; u < 8; ++u) { SGB(0x8, 1); SGB(0x2, 4); }                  \
  }

// C0..C3: chain computation order (wave-parity rotated; chains independent,
// so any order is bit-identical — EPIs follow their own chains).
#define REC_STEP(P, TCUR, C0, C1, C2, C3)                                      \
  {                                                                            \
    i32x4 bfr[8];                                                              \
    float4 qv0, qv1, qv2, qv3;                                                 \
    _Pragma("unroll")                                                          \
    for (int j = 0; j < 4; ++j)                                                \
      xv[(P) ^ 1][j] = *(const uint2*)(xpt + j * 16);                          \
    xpt += ((TCUR) < 510) ? 65536 : 0;                                         \
    bfr[0] = RD8(P, 0);                                                        \
    bfr[1] = RD8(P, 1);                                                        \
    bfr[2] = RD8(P, 2);                                                        \
    MFMA_ONE(C0, 0);                                                           \
    bfr[3] = RD8(P, 3);                                                        \
    MFMA_ONE(C0, 1);                                                           \
    bfr[4] = RD8(P, 4);                                                        \
    MFMA_ONE(C0, 2);                                                           \
    bfr[5] = RD8(P, 5);                                                        \
    MFMA_ONE(C0, 3);                                                           \
    bfr[6] = RD8(P, 6);                                                        \
    MFMA_ONE(C0, 4);                                                           \
    bfr[7] = RD8(P, 7);                                                        \
    MFMA_ONE(C0, 5);                                                           \
    MFMA_ONE(C0, 6);                                                           \
    MFMA_ONE(C0, 7);                                                           \
    SGB(0x20, 4);   /* xv loads issue first */                                 \
    SGB(0x100, 3);  /* 3 ds_reads ahead */                                     \
    SGB(0x8, 1); SGB(0x100, 1);                                                \
    SGB(0x8, 1); SGB(0x100, 1);                                                \
    SGB(0x8, 1); SGB(0x100, 1);                                                \
    SGB(0x8, 1); SGB(0x100, 1);                                                \
    SGB(0x8, 1); SGB(0x100, 1);                                                \
    SGB(0x8, 3);                                                               \
    MFMA_J(C1, bfr);                                                           \
    EPI_MAIN(C0, xv[P], &h2[(P) ^ 1][0], qv0);                                 \
    SGB8_MIX();                                                                \
    EPI_ST(C0, qv0, TCUR);                                                     \
    MFMA_J(C2, bfr);                                                           \
    EPI_MAIN(C1, xv[P], &h2[(P) ^ 1][0], qv1);                                 \
    SGB8_MIX();                                                                \
    EPI_ST(C1, qv1, TCUR);                                                     \
    MFMA_J(C3, bfr);                                                           \
    EPI_MAIN(C2, xv[P], &h2[(P) ^ 1][0], qv2);                                 \
    SGB8_MIX();                                                                \
    EPI_ST(C2, qv2, TCUR);                                                     \
    EPI_MAIN(C3, xv[P], &h2[(P) ^ 1][0], qv3);                                 \
    EPI_ST(C3, qv3, TCUR);                                                     \
    if (MODE == 0) hst += 65536;                                               \
    lds_barrier();                                                             \
  }

template <int MODE>
__global__ __launch_bounds__(512, 2) void rec15_kernel(
    const signed char* __restrict__ Wq,   // [32 jtg][8 kt][64 lane][16] i8
    const float* __restrict__ sc2,        // [512] row scale * 2log2e / 127^2
    const unsigned short* xp,             // [S][B][H] f16 SCALED (aliases hs_out)
    unsigned short* hs_out,               // [S][B][H] bf16
    float* __restrict__ h_last)           // [B][H] fp32
{
    __shared__ unsigned char h2[2][16 * 512];   // 16 KB

    const int tid  = threadIdx.x;
    const int lane = tid & 63;
    const int wave = tid >> 6;              // 0..7
    const int lm   = lane & 15, lq = lane >> 4;
    const int bg   = blockIdx.x;            // 0..63
    const int bb   = bg * 2 + (lm & 1);     // 2 real batches replicated over 16 rows

    // ---- W slice in AGPRs: 4 jtg x 8 kt x int4 = 128 AGPRs per wave ----
    i32x4 wa[4][8];
    #pragma unroll
    for (int j = 0; j < 4; ++j) {
        const int jtg = wave * 4 + j;
        #pragma unroll
        for (int kt = 0; kt < 8; ++kt)
            wa[j][kt] = *(const i32x4*)(Wq + ((size_t)((jtg * 8 + kt) * 64 + lane)) * 16);
    }
    #pragma unroll
    for (int j = 0; j < 4; ++j)
        #pragma unroll
        for (int kt = 0; kt < 8; ++kt)
            PINA(wa[j][kt]);

    // ---- per-lane fused dequant scales, pinned ----
    f32x4 sc[4];
    #pragma unroll
    for (int j = 0; j < 4; ++j)
        sc[j] = *(const f32x4*)(sc2 + (wave * 4 + j) * 16 + lq * 4);
    #pragma unroll
    for (int j = 0; j < 4; ++j) PINV(sc[j]);

    // ---- zero h buffers ----
    for (int i = tid; i < 4096; i += 512) ((int*)h2)[i] = 0;
    __syncthreads();

    // per-thread streaming pointers (row stride 128*512 elems per step)
    const unsigned short* xpt = xp + (size_t)bb * 512 + wave * 64 + lq * 4;
    unsigned short*       hst = hs_out + (size_t)bb * 512 + wave * 64 + lq * 4;

    uint2 xv[2][4];
    i32x4 acc[4];
    const i32x4 z4 = {0, 0, 0, 0};

    // ---- prologue: xv[0] = row 0 ----
    #pragma unroll
    for (int j = 0; j < 4; ++j) xv[0][j] = *(const uint2*)(xpt + j * 16);
    xpt += 65536;

    if ((wave & 1) == 0) {
        for (int t = 0; t < 512; t += 2) {
            REC_STEP(0, t,     0, 1, 2, 3);
            REC_STEP(1, t + 1, 0, 1, 2, 3);
        }
    } else {
        for (int t = 0; t < 512; t += 2) {
            REC_STEP(0, t,     2, 3, 0, 1);
            REC_STEP(1, t + 1, 2, 3, 0, 1);
        }
    }
}

// ---------------------------------------------------------------------------
// head: logits[b][c] = h_last[b][:]·W_out[c][:] + b_out[c]; log_softmax rows.
// ---------------------------------------------------------------------------
__global__ __launch_bounds__(256, 2) void head_kernel(
    const float* __restrict__ hl, const float* __restrict__ Wout,
    const float* __restrict__ bout, float* __restrict__ out)
{
    __shared__ float hrow[512];
    __shared__ float lg[1000];
    __shared__ float red[8];
    const int b = blockIdx.x, tid = threadIdx.x;

    hrow[tid]       = hl[(size_t)b * 512 + tid];
    hrow[tid + 256] = hl[(size_t)b * 512 + 256 + tid];
    __syncthreads();

    float lmax = -1e30f;
    for (int c = tid; c < 1000; c += 256) {
        const float4* w4 = (const float4*)(Wout + (size_t)c * 512);
        float a0 = 0.f, a1 = 0.f, a2 = 0.f, a3 = 0.f;
        #pragma unroll 4
        for (int k = 0; k < 128; ++k) {
            float4 w = w4[k];
            a0 += hrow[4 * k + 0] * w.x;
            a1 += hrow[4 * k + 1] * w.y;
            a2 += hrow[4 * k + 2] * w.z;
            a3 += hrow[4 * k + 3] * w.w;
        }
        float acc = bout[c] + (a0 + a1) + (a2 + a3);
        lg[c] = acc;
        lmax = fmaxf(lmax, acc);
    }
    #pragma unroll
    for (int off = 32; off; off >>= 1) lmax = fmaxf(lmax, __shfl_down(lmax, off, 64));
    if ((tid & 63) == 0) red[tid >> 6] = lmax;
    __syncthreads();
    if (tid == 0) red[4] = fmaxf(fmaxf(red[0], red[1]), fmaxf(red[2], red[3]));
    __syncthreads();
    const float M = red[4];

    float lsum = 0.f;
    for (int c = tid; c < 1000; c += 256) lsum += __expf(lg[c] - M);
    #pragma unroll
    for (int off = 32; off; off >>= 1) lsum += __shfl_down(lsum, off, 64);
    __syncthreads();
    if ((tid & 63) == 0) red[tid >> 6] = lsum;
    __syncthreads();
    if (tid == 0) red[5] = M + __logf(red[0] + red[1] + red[2] + red[3]);
    __syncthreads();
    const float lse = red[5];

    for (int c = tid; c < 1000; c += 256)
        out[(size_t)b * 1000 + c] = lg[c] - lse;
}

// ---------------------------------------------------------------------------
extern "C" void kernel_launch(void* const* d_in, const int* in_sizes, int n_in,
                              void* d_out, int out_size, void* d_ws, size_t ws_size,
                              hipStream_t stream)
{
    const float* x    = (const float*)d_in[0];
    const float* Wih0 = (const float*)d_in[1];
    const float* Whh0 = (const float*)d_in[2];
    const float* bih0 = (const float*)d_in[3];
    const float* bhh0 = (const float*)d_in[4];
    const float* Wih1 = (const float*)d_in[5];
    const float* Whh1 = (const float*)d_in[6];
    const float* bih1 = (const float*)d_in[7];
    const float* bhh1 = (const float*)d_in[8];
    const float* Wout = (const float*)d_in[9];
    const float* bout = (const float*)d_in[10];
    float* out = (float*)d_out;

    char* ws = (char*)d_ws;
    unsigned short* bufA = (unsigned short*)ws;                              // 64 MB
    unsigned short* bufB = (unsigned short*)(ws + (size_t)64 * 1024 * 1024);
    signed char* Wq0 = (signed char*)bufB;                                   // 256 KB (dead after rec0)
    float*       sc0 = (float*)((char*)bufB + 262144);                       // 2 KB
    signed char* Wq1 = (signed char*)bufA;                                   // 256 KB (after proj1 consumed bufA)
    float*       sc1 = (float*)(ws + 262144);                                // 2 KB
    float*     hlast = (float*)(ws + (size_t)1 * 1024 * 1024);               // 256 KB

    const dim3 pgrid(8, 512);

    packi8_kernel<<<512, 64, 0, stream>>>(Whh0, Wq0, sc0);
    proj_kernel<128, 0><<<pgrid, 256, 0, stream>>>((const void*)x, Wih0, bih0, bhh0, bufA, TWO_LOG2E);
    rec15_kernel<0><<<64, 512, 0, stream>>>(Wq0, sc0, bufA, bufA, hlast);

    proj_kernel<512, 1><<<pgrid, 256, 0, stream>>>((const void*)bufA, Wih1, bih1, bhh1, bufB, TWO_LOG2E);
    packi8_kernel<<<512, 64, 0, stream>>>(Whh1, Wq1, sc1);
    rec15_kernel<1><<<64, 512, 0, stream>>>(Wq1, sc1, bufB, bufB, hlast);

    head_kernel<<<128, 256, 0, stream>>>(hlast, Wout, bout, out);
}